// Round 3
// baseline (625.067 us; speedup 1.0000x reference)
//
#include <hip/hip_runtime.h>

#define N_NODES 100000
#define IN_CH 128
#define HIDDEN 128
#define OUT_CH 64
#define N_POS 600000
#define N_NEG 600000

// ================= CSR build =================
__global__ void hist_count(const int* __restrict__ dst, int* __restrict__ hist, int n_edges) {
    int i = blockIdx.x * blockDim.x + threadIdx.x;
    if (i < n_edges) atomicAdd(&hist[dst[i]], 1);
}

// per-1024-chunk sums
__global__ void scan_reduce(const int* __restrict__ hist, int* __restrict__ partials, int n) {
    __shared__ int sdata[256];
    int b = blockIdx.x, t = threadIdx.x;
    int base = b * 1024;
    int s = 0;
    for (int i = t; i < 1024; i += 256) {
        int idx = base + i;
        s += (idx < n) ? hist[idx] : 0;
    }
    sdata[t] = s;
    __syncthreads();
    for (int off = 128; off > 0; off >>= 1) {
        if (t < off) sdata[t] += sdata[t + off];
        __syncthreads();
    }
    if (t == 0) partials[b] = sdata[0];
}

// exclusive scan of partials (nb <= 128), single block of 128 threads
__global__ void scan_partials(int* __restrict__ partials, int nb) {
    __shared__ int tmp[128];
    int t = threadIdx.x;
    int v = (t < nb) ? partials[t] : 0;
    tmp[t] = v;
    __syncthreads();
    for (int off = 1; off < 128; off <<= 1) {
        int a = (t >= off) ? tmp[t - off] : 0;
        __syncthreads();
        tmp[t] += a;
        __syncthreads();
    }
    if (t < nb) partials[t] = tmp[t] - v;  // exclusive
}

// rowstart/cursor/dinv from hist + scanned partials
__global__ void scan_final(const int* __restrict__ hist, const int* __restrict__ partials,
                           int* __restrict__ rowstart, int* __restrict__ cursor,
                           float* __restrict__ dinv, int n) {
    __shared__ int tsum[256];
    int t = threadIdx.x, b = blockIdx.x;
    int base = b * 1024 + t * 4;
    int v[4];
    int s = 0;
#pragma unroll
    for (int j = 0; j < 4; j++) {
        int i = base + j;
        v[j] = (i < n) ? hist[i] : 0;
        s += v[j];
    }
    tsum[t] = s;
    __syncthreads();
    for (int off = 1; off < 256; off <<= 1) {
        int a = (t >= off) ? tsum[t - off] : 0;
        __syncthreads();
        tsum[t] += a;
        __syncthreads();
    }
    int offset = partials[b] + (tsum[t] - s);
#pragma unroll
    for (int j = 0; j < 4; j++) {
        int i = base + j;
        if (i < n) {
            rowstart[i] = offset;
            cursor[i] = offset;
            dinv[i] = rsqrtf((float)v[j] + 1.0f);
            offset += v[j];
        }
    }
    if (b == 0 && t == 0) rowstart[n] = N_POS;
}

__global__ void csr_fill(const int* __restrict__ src, const int* __restrict__ dst,
                         int* __restrict__ cursor, int* __restrict__ adj, int n_edges) {
    int e = blockIdx.x * blockDim.x + threadIdx.x;
    if (e < n_edges) {
        int p = atomicAdd(&cursor[dst[e]], 1);
        adj[p] = src[e];
    }
}

// ================= tiled fp32 GEMM: H[n,M] = X[n,128] @ W[128,M] =================
// TILE 64 nodes; thread computes 4 nodes x 4 cols; W + padded X tile in LDS.
template <int M, int THREADS>
__global__ __launch_bounds__(THREADS) void linear2(const float* __restrict__ X,
                                                   const float* __restrict__ W,
                                                   float* __restrict__ H, int n) {
    constexpr int K = 128;
    constexpr int TN = 64;
    constexpr int XS = 132;  // padded row stride (floats), 16B-aligned rows
    __shared__ float Ws[K * M];
    __shared__ float Xs[TN * XS];
    int tid = threadIdx.x;
    int node0 = blockIdx.x * TN;

    for (int q = tid; q < K * M / 4; q += THREADS)
        ((float4*)Ws)[q] = ((const float4*)W)[q];
    for (int q = tid; q < TN * K / 4; q += THREADS) {
        int node = q >> 5;   // 32 float4 per row
        int k4 = q & 31;
        int gn = node0 + node;
        float4 v = (gn < n) ? ((const float4*)(X + (size_t)gn * K))[k4] : float4{0, 0, 0, 0};
        ((float4*)(Xs + node * XS))[k4] = v;
    }
    __syncthreads();

    int tn = tid & 15;        // node group: nodes tn + 16*i
    int tj = tid >> 4;        // col group: cols tj*4 .. tj*4+3
    float acc[4][4] = {};
    for (int k = 0; k < K; k += 4) {
        float4 xa[4], wb[4];
#pragma unroll
        for (int i = 0; i < 4; i++)
            xa[i] = *(const float4*)(Xs + (tn + 16 * i) * XS + k);
#pragma unroll
        for (int q = 0; q < 4; q++)
            wb[q] = *(const float4*)(Ws + (k + q) * M + tj * 4);
#pragma unroll
        for (int i = 0; i < 4; i++) {
            float xk[4] = {xa[i].x, xa[i].y, xa[i].z, xa[i].w};
#pragma unroll
            for (int q = 0; q < 4; q++) {
                acc[i][0] += xk[q] * wb[q].x;
                acc[i][1] += xk[q] * wb[q].y;
                acc[i][2] += xk[q] * wb[q].z;
                acc[i][3] += xk[q] * wb[q].w;
            }
        }
    }
#pragma unroll
    for (int i = 0; i < 4; i++) {
        int gn = node0 + tn + 16 * i;
        if (gn < n)
            *(float4*)(H + (size_t)gn * M + tj * 4) =
                float4{acc[i][0], acc[i][1], acc[i][2], acc[i][3]};
    }
}

// ================= fused pull aggregation + self-loop + bias (+relu) =================
// one 64-lane wave per dst node
template <int F, bool RELU>
__global__ void agg_pull(const int* __restrict__ rowstart, const int* __restrict__ adj,
                         const float* __restrict__ dinv, const float* __restrict__ H,
                         const float* __restrict__ bias, float* __restrict__ Z, int n) {
    int wave = threadIdx.x >> 6;
    int lane = threadIdx.x & 63;
    int node = blockIdx.x * (blockDim.x >> 6) + wave;
    if (node >= n) return;
    float dn = dinv[node];
    int rs = rowstart[node], re = rowstart[node + 1];
    if (F == 128) {
        float2 acc = {0.0f, 0.0f};
        for (int p = rs; p < re; ++p) {
            int s = adj[p];
            float w = dinv[s] * dn;
            float2 hv = *(const float2*)(H + (size_t)s * F + lane * 2);
            acc.x += hv.x * w;
            acc.y += hv.y * w;
        }
        float2 hv = *(const float2*)(H + (size_t)node * F + lane * 2);
        float2 bv = *(const float2*)(bias + lane * 2);
        float vx = acc.x + hv.x * dn * dn + bv.x;
        float vy = acc.y + hv.y * dn * dn + bv.y;
        if (RELU) {
            vx = fmaxf(vx, 0.0f);
            vy = fmaxf(vy, 0.0f);
        }
        *(float2*)(Z + (size_t)node * F + lane * 2) = float2{vx, vy};
    } else {  // F == 64
        float acc = 0.0f;
        for (int p = rs; p < re; ++p) {
            int s = adj[p];
            acc += H[(size_t)s * F + lane] * (dinv[s] * dn);
        }
        float v = acc + H[(size_t)node * F + lane] * dn * dn + bias[lane];
        if (RELU) v = fmaxf(v, 0.0f);
        Z[(size_t)node * F + lane] = v;
    }
}

// ================= decode: out[e] = dot64(Z[a], Z[b]), one THREAD per edge =================
// 32 independent float4 loads per edge -> deep ILP over the random-gather latency;
// ~1.7 wave-instructions/edge vs ~15 for the old wave-per-edge shuffle reduction.
__global__ void decode_kernel(const int* __restrict__ pos, const int* __restrict__ neg,
                              const float* __restrict__ Z, float* __restrict__ out) {
    int e = blockIdx.x * blockDim.x + threadIdx.x;
    if (e >= N_POS + N_NEG) return;
    int a, b;
    if (e < N_POS) {
        a = pos[e];
        b = pos[N_POS + e];
    } else {
        int e2 = e - N_POS;
        a = neg[e2];
        b = neg[N_NEG + e2];
    }
    const float4* za = (const float4*)(Z + (size_t)a * OUT_CH);
    const float4* zb = (const float4*)(Z + (size_t)b * OUT_CH);
    float acc = 0.0f;
#pragma unroll
    for (int q = 0; q < OUT_CH / 4; ++q) {
        float4 va = za[q];
        float4 vb = zb[q];
        acc += va.x * vb.x + va.y * vb.y + va.z * vb.z + va.w * vb.w;
    }
    out[e] = acc;
}

extern "C" void kernel_launch(void* const* d_in, const int* in_sizes, int n_in,
                              void* d_out, int out_size, void* d_ws, size_t ws_size,
                              hipStream_t stream) {
    const float* x = (const float*)d_in[0];
    const int* pos = (const int*)d_in[1];  // row0 = src, row1 = dst
    const int* neg = (const int*)d_in[2];
    const float* W1 = (const float*)d_in[3];
    const float* b1 = (const float*)d_in[4];
    const float* W2 = (const float*)d_in[5];
    const float* b2 = (const float*)d_in[6];
    float* out = (float*)d_out;

    // workspace layout
    float* A = (float*)d_ws;                        // h1 [N,128]; later h2 [N,64]
    float* B = A + (size_t)N_NODES * 128;           // z1 [N,128]; later z2 [N,64]
    float* dinv = B + (size_t)N_NODES * 128;        // [N]
    int* hist = (int*)(dinv + N_NODES);             // [N]
    int* rowstart = hist + N_NODES;                 // [N+1]
    int* cursor = rowstart + N_NODES + 1;           // [N]
    int* adj = cursor + N_NODES;                    // [N_POS]
    int* partials = adj + N_POS;                    // [128]

    const int* pos_src = pos;
    const int* pos_dst = pos + N_POS;

    constexpr int NB_SCAN = (N_NODES + 1023) / 1024;  // 98

    // ---- CSR build + dinv ----
    hipMemsetAsync(hist, 0, N_NODES * sizeof(int), stream);
    hist_count<<<(N_POS + 255) / 256, 256, 0, stream>>>(pos_dst, hist, N_POS);
    scan_reduce<<<NB_SCAN, 256, 0, stream>>>(hist, partials, N_NODES);
    scan_partials<<<1, 128, 0, stream>>>(partials, NB_SCAN);
    scan_final<<<NB_SCAN, 256, 0, stream>>>(hist, partials, rowstart, cursor, dinv, N_NODES);
    csr_fill<<<(N_POS + 255) / 256, 256, 0, stream>>>(pos_src, pos_dst, cursor, adj, N_POS);

    // ---- layer 1 ----
    linear2<HIDDEN, 512><<<(N_NODES + 63) / 64, 512, 0, stream>>>(x, W1, A, N_NODES);
    agg_pull<HIDDEN, true><<<(N_NODES + 3) / 4, 256, 0, stream>>>(rowstart, adj, dinv, A, b1, B,
                                                                  N_NODES);

    // ---- layer 2 ----
    float* h2 = A;  // [N,64]
    linear2<OUT_CH, 256><<<(N_NODES + 63) / 64, 256, 0, stream>>>(B, W2, h2, N_NODES);
    float* z2 = B;  // [N,64]
    agg_pull<OUT_CH, false><<<(N_NODES + 3) / 4, 256, 0, stream>>>(rowstart, adj, dinv, h2, b2, z2,
                                                                   N_NODES);

    // ---- decode ----
    decode_kernel<<<(N_POS + N_NEG + 255) / 256, 256, 0, stream>>>(pos, neg, z2, out);
}

// Round 4
// 444.866 us; speedup vs baseline: 1.4051x; 1.4051x over previous
//
#include <hip/hip_runtime.h>

#define N_NODES 100000
#define IN_CH 128
#define HIDDEN 128
#define OUT_CH 64
#define N_POS 600000
#define N_NEG 600000

typedef unsigned int uint32;
typedef unsigned short ushort16;

// ---- bf16 helpers (fp32 storage halved; accumulate in fp32) ----
__device__ inline float bf_lo(uint32 u) {
    union { uint32 i; float f; } v;
    v.i = u << 16;
    return v.f;
}
__device__ inline float bf_hi(uint32 u) {
    union { uint32 i; float f; } v;
    v.i = u & 0xffff0000u;
    return v.f;
}
__device__ inline ushort16 f2bf(float f) {
    union { uint32 i; float f; } v;
    v.f = f;
    uint32 r = v.i + 0x7fffu + ((v.i >> 16) & 1u);  // round-to-nearest-even
    return (ushort16)(r >> 16);
}
__device__ inline uint32 pack2bf(float a, float b) {
    return (uint32)f2bf(a) | ((uint32)f2bf(b) << 16);
}

// ================= CSR build =================
__global__ void hist_count(const int* __restrict__ dst, int* __restrict__ hist, int n_edges) {
    int i = blockIdx.x * blockDim.x + threadIdx.x;
    if (i < n_edges) atomicAdd(&hist[dst[i]], 1);
}

__global__ void scan_reduce(const int* __restrict__ hist, int* __restrict__ partials, int n) {
    __shared__ int sdata[256];
    int b = blockIdx.x, t = threadIdx.x;
    int base = b * 1024;
    int s = 0;
    for (int i = t; i < 1024; i += 256) {
        int idx = base + i;
        s += (idx < n) ? hist[idx] : 0;
    }
    sdata[t] = s;
    __syncthreads();
    for (int off = 128; off > 0; off >>= 1) {
        if (t < off) sdata[t] += sdata[t + off];
        __syncthreads();
    }
    if (t == 0) partials[b] = sdata[0];
}

__global__ void scan_partials(int* __restrict__ partials, int nb) {
    __shared__ int tmp[128];
    int t = threadIdx.x;
    int v = (t < nb) ? partials[t] : 0;
    tmp[t] = v;
    __syncthreads();
    for (int off = 1; off < 128; off <<= 1) {
        int a = (t >= off) ? tmp[t - off] : 0;
        __syncthreads();
        tmp[t] += a;
        __syncthreads();
    }
    if (t < nb) partials[t] = tmp[t] - v;  // exclusive
}

__global__ void scan_final(const int* __restrict__ hist, const int* __restrict__ partials,
                           int* __restrict__ rowstart, int* __restrict__ cursor,
                           float* __restrict__ dinv, int n) {
    __shared__ int tsum[256];
    int t = threadIdx.x, b = blockIdx.x;
    int base = b * 1024 + t * 4;
    int v[4];
    int s = 0;
#pragma unroll
    for (int j = 0; j < 4; j++) {
        int i = base + j;
        v[j] = (i < n) ? hist[i] : 0;
        s += v[j];
    }
    tsum[t] = s;
    __syncthreads();
    for (int off = 1; off < 256; off <<= 1) {
        int a = (t >= off) ? tsum[t - off] : 0;
        __syncthreads();
        tsum[t] += a;
        __syncthreads();
    }
    int offset = partials[b] + (tsum[t] - s);
#pragma unroll
    for (int j = 0; j < 4; j++) {
        int i = base + j;
        if (i < n) {
            rowstart[i] = offset;
            cursor[i] = offset;
            dinv[i] = rsqrtf((float)v[j] + 1.0f);
            offset += v[j];
        }
    }
    if (b == 0 && t == 0) rowstart[n] = N_POS;
}

__global__ void csr_fill(const int* __restrict__ src, const int* __restrict__ dst,
                         int* __restrict__ cursor, int* __restrict__ adj, int n_edges) {
    int e = blockIdx.x * blockDim.x + threadIdx.x;
    if (e < n_edges) {
        int p = atomicAdd(&cursor[dst[e]], 1);
        adj[p] = src[e];
    }
}

// ================= tiled GEMM: H_bf16[n,M] = X[n,128] @ W[128,M] =================
// X is fp32 (XBF=false) or bf16 (XBF=true); W fp32; accumulate fp32; output bf16.
template <int M, int THREADS, bool XBF>
__global__ __launch_bounds__(THREADS) void linear2(const void* __restrict__ Xv,
                                                   const float* __restrict__ W,
                                                   ushort16* __restrict__ H, int n) {
    constexpr int K = 128;
    constexpr int TN = 64;
    constexpr int XS = 132;  // padded LDS row stride (floats)
    __shared__ float Ws[K * M];
    __shared__ float Xs[TN * XS];
    int tid = threadIdx.x;
    int node0 = blockIdx.x * TN;

    for (int q = tid; q < K * M / 4; q += THREADS)
        ((float4*)Ws)[q] = ((const float4*)W)[q];

    if (!XBF) {
        const float* X = (const float*)Xv;
        for (int q = tid; q < TN * K / 4; q += THREADS) {
            int node = q >> 5;  // 32 float4 per row
            int k4 = q & 31;
            int gn = node0 + node;
            float4 v = (gn < n) ? ((const float4*)(X + (size_t)gn * K))[k4] : float4{0, 0, 0, 0};
            ((float4*)(Xs + node * XS))[k4] = v;
        }
    } else {
        const ushort16* X = (const ushort16*)Xv;
        for (int q = tid; q < TN * K / 8; q += THREADS) {
            int node = q >> 4;  // 16 x (8 bf16) per row
            int k8 = q & 15;
            int gn = node0 + node;
            uint4 v = (gn < n) ? ((const uint4*)(X + (size_t)gn * K))[k8] : uint4{0, 0, 0, 0};
            float* dst = Xs + node * XS + k8 * 8;
            dst[0] = bf_lo(v.x); dst[1] = bf_hi(v.x);
            dst[2] = bf_lo(v.y); dst[3] = bf_hi(v.y);
            dst[4] = bf_lo(v.z); dst[5] = bf_hi(v.z);
            dst[6] = bf_lo(v.w); dst[7] = bf_hi(v.w);
        }
    }
    __syncthreads();

    int tn = tid & 15;  // nodes tn + 16*i
    int tj = tid >> 4;  // cols tj*4 .. tj*4+3
    float acc[4][4] = {};
    for (int k = 0; k < K; k += 4) {
        float4 xa[4], wb[4];
#pragma unroll
        for (int i = 0; i < 4; i++)
            xa[i] = *(const float4*)(Xs + (tn + 16 * i) * XS + k);
#pragma unroll
        for (int q = 0; q < 4; q++)
            wb[q] = *(const float4*)(Ws + (k + q) * M + tj * 4);
#pragma unroll
        for (int i = 0; i < 4; i++) {
            float xk[4] = {xa[i].x, xa[i].y, xa[i].z, xa[i].w};
#pragma unroll
            for (int q = 0; q < 4; q++) {
                acc[i][0] += xk[q] * wb[q].x;
                acc[i][1] += xk[q] * wb[q].y;
                acc[i][2] += xk[q] * wb[q].z;
                acc[i][3] += xk[q] * wb[q].w;
            }
        }
    }
#pragma unroll
    for (int i = 0; i < 4; i++) {
        int gn = node0 + tn + 16 * i;
        if (gn < n) {
            uint32 p0 = pack2bf(acc[i][0], acc[i][1]);
            uint32 p1 = pack2bf(acc[i][2], acc[i][3]);
            *(uint2*)(H + (size_t)gn * M + tj * 4) = uint2{p0, p1};
        }
    }
}

// ========= fused pull aggregation + self-loop + bias (+relu), bf16 H/Z =========
// one 64-lane wave per dst node; fp32 accumulate
template <int F, bool RELU>
__global__ void agg_pull(const int* __restrict__ rowstart, const int* __restrict__ adj,
                         const float* __restrict__ dinv, const ushort16* __restrict__ H,
                         const float* __restrict__ bias, ushort16* __restrict__ Z, int n) {
    int wave = threadIdx.x >> 6;
    int lane = threadIdx.x & 63;
    int node = blockIdx.x * (blockDim.x >> 6) + wave;
    if (node >= n) return;
    float dn = dinv[node];
    int rs = rowstart[node], re = rowstart[node + 1];
    if (F == 128) {
        float ax = 0.0f, ay = 0.0f;
        for (int p = rs; p < re; ++p) {
            int s = adj[p];
            float w = dinv[s] * dn;
            uint32 hv = *(const uint32*)(H + (size_t)s * F + lane * 2);  // 2 bf16, 4B/lane
            ax += bf_lo(hv) * w;
            ay += bf_hi(hv) * w;
        }
        uint32 hv = *(const uint32*)(H + (size_t)node * F + lane * 2);
        float2 bv = *(const float2*)(bias + lane * 2);
        float vx = ax + bf_lo(hv) * dn * dn + bv.x;
        float vy = ay + bf_hi(hv) * dn * dn + bv.y;
        if (RELU) {
            vx = fmaxf(vx, 0.0f);
            vy = fmaxf(vy, 0.0f);
        }
        *(uint32*)(Z + (size_t)node * F + lane * 2) = pack2bf(vx, vy);
    } else {  // F == 64: 2B/lane, full 128B row per instruction
        float acc = 0.0f;
        for (int p = rs; p < re; ++p) {
            int s = adj[p];
            float h = bf_lo((uint32)H[(size_t)s * F + lane]);
            acc += h * (dinv[s] * dn);
        }
        float h = bf_lo((uint32)H[(size_t)node * F + lane]);
        float v = acc + h * dn * dn + bias[lane];
        if (RELU) v = fmaxf(v, 0.0f);
        Z[(size_t)node * F + lane] = f2bf(v);
    }
}

// ===== decode: out[e] = dot64(Z[a], Z[b]); 16 lanes per edge, bf16 rows =====
// Each lane loads 8B (4 bf16) -> 16 lanes cover the full 128B row in ONE
// coalesced line-fetch per row. 4 edges per wave; 4-step shuffle reduce.
__global__ void decode_kernel(const int* __restrict__ pos, const int* __restrict__ neg,
                              const ushort16* __restrict__ Z, float* __restrict__ out) {
    int wid = threadIdx.x >> 6;
    int lane = threadIdx.x & 63;
    int g = lane >> 4;   // edge slot within wave
    int l = lane & 15;   // lane within edge
    int e = (blockIdx.x * (blockDim.x >> 6) + wid) * 4 + g;
    if (e >= N_POS + N_NEG) return;
    int a, b;
    if (e < N_POS) {
        a = pos[e];
        b = pos[N_POS + e];
    } else {
        int e2 = e - N_POS;
        a = neg[e2];
        b = neg[N_NEG + e2];
    }
    uint2 ua = *(const uint2*)(Z + (size_t)a * OUT_CH + l * 4);
    uint2 ub = *(const uint2*)(Z + (size_t)b * OUT_CH + l * 4);
    float acc = bf_lo(ua.x) * bf_lo(ub.x) + bf_hi(ua.x) * bf_hi(ub.x) +
                bf_lo(ua.y) * bf_lo(ub.y) + bf_hi(ua.y) * bf_hi(ub.y);
#pragma unroll
    for (int off = 8; off > 0; off >>= 1) acc += __shfl_down(acc, off, 16);
    if (l == 0) out[e] = acc;
}

extern "C" void kernel_launch(void* const* d_in, const int* in_sizes, int n_in,
                              void* d_out, int out_size, void* d_ws, size_t ws_size,
                              hipStream_t stream) {
    const float* x = (const float*)d_in[0];
    const int* pos = (const int*)d_in[1];  // row0 = src, row1 = dst
    const int* neg = (const int*)d_in[2];
    const float* W1 = (const float*)d_in[3];
    const float* b1 = (const float*)d_in[4];
    const float* W2 = (const float*)d_in[5];
    const float* b2 = (const float*)d_in[6];
    float* out = (float*)d_out;

    // workspace layout (bf16 intermediates)
    ushort16* A = (ushort16*)d_ws;                   // h1 [N,128]; later h2 [N,64]
    ushort16* B = A + (size_t)N_NODES * 128;         // z1 [N,128]; later z2 [N,64]
    float* dinv = (float*)(B + (size_t)N_NODES * 128);  // [N]
    int* hist = (int*)(dinv + N_NODES);              // [N]
    int* rowstart = hist + N_NODES;                  // [N+1]
    int* cursor = rowstart + N_NODES + 1;            // [N]
    int* adj = cursor + N_NODES;                     // [N_POS]
    int* partials = adj + N_POS;                     // [128]

    const int* pos_src = pos;
    const int* pos_dst = pos + N_POS;

    constexpr int NB_SCAN = (N_NODES + 1023) / 1024;  // 98

    // ---- CSR build + dinv ----
    hipMemsetAsync(hist, 0, N_NODES * sizeof(int), stream);
    hist_count<<<(N_POS + 255) / 256, 256, 0, stream>>>(pos_dst, hist, N_POS);
    scan_reduce<<<NB_SCAN, 256, 0, stream>>>(hist, partials, N_NODES);
    scan_partials<<<1, 128, 0, stream>>>(partials, NB_SCAN);
    scan_final<<<NB_SCAN, 256, 0, stream>>>(hist, partials, rowstart, cursor, dinv, N_NODES);
    csr_fill<<<(N_POS + 255) / 256, 256, 0, stream>>>(pos_src, pos_dst, cursor, adj, N_POS);

    // ---- layer 1 ----
    linear2<HIDDEN, 512, false><<<(N_NODES + 63) / 64, 512, 0, stream>>>(x, W1, A, N_NODES);
    agg_pull<HIDDEN, true><<<(N_NODES + 3) / 4, 256, 0, stream>>>(rowstart, adj, dinv, A, b1, B,
                                                                  N_NODES);

    // ---- layer 2 ----
    ushort16* h2 = A;  // [N,64]
    linear2<OUT_CH, 256, true><<<(N_NODES + 63) / 64, 256, 0, stream>>>(B, W2, h2, N_NODES);
    ushort16* z2 = B;  // [N,64]
    agg_pull<OUT_CH, false><<<(N_NODES + 3) / 4, 256, 0, stream>>>(rowstart, adj, dinv, h2, b2, z2,
                                                                   N_NODES);

    // ---- decode ----
    int edges_per_block = (256 / 64) * 4;  // 16
    decode_kernel<<<(N_POS + N_NEG + edges_per_block - 1) / edges_per_block, 256, 0, stream>>>(
        pos, neg, z2, out);
}

// Round 5
// 389.666 us; speedup vs baseline: 1.6041x; 1.1417x over previous
//
#include <hip/hip_runtime.h>

#define N_NODES 100000
#define IN_CH 128
#define HIDDEN 128
#define OUT_CH 64
#define N_POS 600000
#define N_NEG 600000

typedef unsigned int uint32;
typedef unsigned short ushort16;
typedef __attribute__((ext_vector_type(8))) short bf16x8;
typedef __attribute__((ext_vector_type(4))) float f32x4;

// ---- bf16 helpers ----
__device__ inline float bf_lo(uint32 u) {
    union { uint32 i; float f; } v;
    v.i = u << 16;
    return v.f;
}
__device__ inline float bf_hi(uint32 u) {
    union { uint32 i; float f; } v;
    v.i = u & 0xffff0000u;
    return v.f;
}
__device__ inline ushort16 f2bf(float f) {
    union { uint32 i; float f; } v;
    v.f = f;
    uint32 r = v.i + 0x7fffu + ((v.i >> 16) & 1u);  // round-to-nearest-even
    return (ushort16)(r >> 16);
}
__device__ inline uint32 pack2bf(float a, float b) {
    return (uint32)f2bf(a) | ((uint32)f2bf(b) << 16);
}

// ================= CSR build =================
__global__ void hist_count(const int* __restrict__ dst, int* __restrict__ hist, int n_edges) {
    int i = blockIdx.x * blockDim.x + threadIdx.x;
    if (i < n_edges) atomicAdd(&hist[dst[i]], 1);
}

__global__ void scan_reduce(const int* __restrict__ hist, int* __restrict__ partials, int n) {
    __shared__ int sdata[256];
    int b = blockIdx.x, t = threadIdx.x;
    int base = b * 1024;
    int s = 0;
    for (int i = t; i < 1024; i += 256) {
        int idx = base + i;
        s += (idx < n) ? hist[idx] : 0;
    }
    sdata[t] = s;
    __syncthreads();
    for (int off = 128; off > 0; off >>= 1) {
        if (t < off) sdata[t] += sdata[t + off];
        __syncthreads();
    }
    if (t == 0) partials[b] = sdata[0];
}

__global__ void scan_partials(int* __restrict__ partials, int nb) {
    __shared__ int tmp[128];
    int t = threadIdx.x;
    int v = (t < nb) ? partials[t] : 0;
    tmp[t] = v;
    __syncthreads();
    for (int off = 1; off < 128; off <<= 1) {
        int a = (t >= off) ? tmp[t - off] : 0;
        __syncthreads();
        tmp[t] += a;
        __syncthreads();
    }
    if (t < nb) partials[t] = tmp[t] - v;  // exclusive
}

__global__ void scan_final(const int* __restrict__ hist, const int* __restrict__ partials,
                           int* __restrict__ rowstart, int* __restrict__ cursor,
                           float* __restrict__ dinv, int n) {
    __shared__ int tsum[256];
    int t = threadIdx.x, b = blockIdx.x;
    int base = b * 1024 + t * 4;
    int v[4];
    int s = 0;
#pragma unroll
    for (int j = 0; j < 4; j++) {
        int i = base + j;
        v[j] = (i < n) ? hist[i] : 0;
        s += v[j];
    }
    tsum[t] = s;
    __syncthreads();
    for (int off = 1; off < 256; off <<= 1) {
        int a = (t >= off) ? tsum[t - off] : 0;
        __syncthreads();
        tsum[t] += a;
        __syncthreads();
    }
    int offset = partials[b] + (tsum[t] - s);
#pragma unroll
    for (int j = 0; j < 4; j++) {
        int i = base + j;
        if (i < n) {
            rowstart[i] = offset;
            cursor[i] = offset;
            dinv[i] = rsqrtf((float)v[j] + 1.0f);
            offset += v[j];
        }
    }
    if (b == 0 && t == 0) rowstart[n] = N_POS;
}

__global__ void csr_fill(const int* __restrict__ src, const int* __restrict__ dst,
                         int* __restrict__ cursor, int* __restrict__ adj, int n_edges) {
    int e = blockIdx.x * blockDim.x + threadIdx.x;
    if (e < n_edges) {
        int p = atomicAdd(&cursor[dst[e]], 1);
        adj[p] = src[e];
    }
}

// ===== one-shot: W1t[n][k]=bf16(W1[k][n]) (128x128), W2t[n][k]=bf16(W2[k][n]) (64x128) =====
__global__ void wt_convert(const float* __restrict__ W1, const float* __restrict__ W2,
                           ushort16* __restrict__ W1t, ushort16* __restrict__ W2t) {
    int i = blockIdx.x * blockDim.x + threadIdx.x;
    if (i < 128 * 128) {
        int n = i >> 7, k = i & 127;
        W1t[i] = f2bf(W1[k * 128 + n]);
    } else {
        int j = i - 128 * 128;
        if (j < 64 * 128) {
            int n = j >> 7, k = j & 127;
            W2t[j] = f2bf(W2[k * 64 + n]);
        }
    }
}

// ================= MFMA GEMM: H_bf16[n,M] = X[n,128] @ W[128,M] =================
// K=128 staged entirely in LDS. Wt is bf16 [M][K] (transposed). 256 threads,
// 64-node tile, wave w owns row-tile w; XS=136 shorts pad -> 2-way bank alias (free).
template <int M, bool XBF>
__global__ __launch_bounds__(256) void gemm_mfma(const void* __restrict__ Xv,
                                                const ushort16* __restrict__ Wt,
                                                ushort16* __restrict__ H, int n) {
    constexpr int K = 128;
    constexpr int TN = 64;
    constexpr int XS = 136;  // padded LDS row stride (shorts), 16B-aligned
    __shared__ short Xs[TN * XS];
    __shared__ short Ws[M * XS];
    int tid = threadIdx.x;
    int node0 = blockIdx.x * TN;

    // stage Wt (bf16, [M][128]) into padded LDS rows
    for (int q = tid; q < M * K / 8; q += 256) {
        int row = q >> 4;   // 16 chunks of 8 shorts per row
        int c = q & 15;
        uint4 v = ((const uint4*)Wt)[q];
        *(uint4*)(Ws + row * XS + c * 8) = v;
    }
    // stage X tile
    if (!XBF) {
        const float* X = (const float*)Xv;
        // 4 threads per row, each handles 32 floats (8 float4) -> pack bf16
        int row = tid >> 2, part = tid & 3;
        int gn = node0 + row;
#pragma unroll
        for (int c = 0; c < 8; ++c) {
            int k = part * 32 + c * 4;
            float4 v = (gn < n) ? *(const float4*)(X + (size_t)gn * K + k) : float4{0, 0, 0, 0};
            uint2 p = {pack2bf(v.x, v.y), pack2bf(v.z, v.w)};
            *(uint2*)(Xs + row * XS + k) = p;
        }
    } else {
        const ushort16* X = (const ushort16*)Xv;
        for (int q = tid; q < TN * K / 8; q += 256) {
            int row = q >> 4;
            int c = q & 15;
            int gn = node0 + row;
            uint4 v = (gn < n) ? ((const uint4*)(X + (size_t)gn * K))[c] : uint4{0, 0, 0, 0};
            *(uint4*)(Xs + row * XS + c * 8) = v;
        }
    }
    __syncthreads();

    constexpr int CT = M / 16;  // col tiles per wave
    int w = tid >> 6;           // wave = row-tile
    int lane = tid & 63;
    int l15 = lane & 15;
    int quad = lane >> 4;

    f32x4 acc[CT] = {};
    const short* xrow = Xs + (w * 16 + l15) * XS + quad * 8;
#pragma unroll
    for (int kk = 0; kk < 4; ++kk) {
        bf16x8 a = *(const bf16x8*)(xrow + kk * 32);
#pragma unroll
        for (int ct = 0; ct < CT; ++ct) {
            bf16x8 b = *(const bf16x8*)(Ws + (ct * 16 + l15) * XS + quad * 8 + kk * 32);
            acc[ct] = __builtin_amdgcn_mfma_f32_16x16x32_bf16(a, b, acc[ct], 0, 0, 0);
        }
    }

    // C/D: row = quad*4 + r, col = l15 (within each 16x16 tile)
#pragma unroll
    for (int ct = 0; ct < CT; ++ct) {
#pragma unroll
        for (int r = 0; r < 4; ++r) {
            int gn = node0 + w * 16 + quad * 4 + r;
            if (gn < n) H[(size_t)gn * M + ct * 16 + l15] = f2bf(acc[ct][r]);
        }
    }
}

// ========= fused pull aggregation + self-loop + bias (+relu), bf16 H/Z =========
template <int F, bool RELU>
__global__ void agg_pull(const int* __restrict__ rowstart, const int* __restrict__ adj,
                         const float* __restrict__ dinv, const ushort16* __restrict__ H,
                         const float* __restrict__ bias, ushort16* __restrict__ Z, int n) {
    int wave = threadIdx.x >> 6;
    int lane = threadIdx.x & 63;
    int node = blockIdx.x * (blockDim.x >> 6) + wave;
    if (node >= n) return;
    float dn = dinv[node];
    int rs = rowstart[node], re = rowstart[node + 1];
    if (F == 128) {
        float ax = 0.0f, ay = 0.0f;
        for (int p = rs; p < re; ++p) {
            int s = adj[p];
            float w = dinv[s] * dn;
            uint32 hv = *(const uint32*)(H + (size_t)s * F + lane * 2);
            ax += bf_lo(hv) * w;
            ay += bf_hi(hv) * w;
        }
        uint32 hv = *(const uint32*)(H + (size_t)node * F + lane * 2);
        float2 bv = *(const float2*)(bias + lane * 2);
        float vx = ax + bf_lo(hv) * dn * dn + bv.x;
        float vy = ay + bf_hi(hv) * dn * dn + bv.y;
        if (RELU) {
            vx = fmaxf(vx, 0.0f);
            vy = fmaxf(vy, 0.0f);
        }
        *(uint32*)(Z + (size_t)node * F + lane * 2) = pack2bf(vx, vy);
    } else {  // F == 64
        float acc = 0.0f;
        for (int p = rs; p < re; ++p) {
            int s = adj[p];
            float h = bf_lo((uint32)H[(size_t)s * F + lane]);
            acc += h * (dinv[s] * dn);
        }
        float h = bf_lo((uint32)H[(size_t)node * F + lane]);
        float v = acc + h * dn * dn + bias[lane];
        if (RELU) v = fmaxf(v, 0.0f);
        Z[(size_t)node * F + lane] = f2bf(v);
    }
}

// ===== decode: 16 lanes per edge, bf16 rows; one line-fetch per row =====
__global__ void decode_kernel(const int* __restrict__ pos, const int* __restrict__ neg,
                              const ushort16* __restrict__ Z, float* __restrict__ out) {
    int wid = threadIdx.x >> 6;
    int lane = threadIdx.x & 63;
    int g = lane >> 4;
    int l = lane & 15;
    int e = (blockIdx.x * (blockDim.x >> 6) + wid) * 4 + g;
    if (e >= N_POS + N_NEG) return;
    int a, b;
    if (e < N_POS) {
        a = pos[e];
        b = pos[N_POS + e];
    } else {
        int e2 = e - N_POS;
        a = neg[e2];
        b = neg[N_NEG + e2];
    }
    uint2 ua = *(const uint2*)(Z + (size_t)a * OUT_CH + l * 4);
    uint2 ub = *(const uint2*)(Z + (size_t)b * OUT_CH + l * 4);
    float acc = bf_lo(ua.x) * bf_lo(ub.x) + bf_hi(ua.x) * bf_hi(ub.x) +
                bf_lo(ua.y) * bf_lo(ub.y) + bf_hi(ua.y) * bf_hi(ub.y);
#pragma unroll
    for (int off = 8; off > 0; off >>= 1) acc += __shfl_down(acc, off, 16);
    if (l == 0) out[e] = acc;
}

extern "C" void kernel_launch(void* const* d_in, const int* in_sizes, int n_in,
                              void* d_out, int out_size, void* d_ws, size_t ws_size,
                              hipStream_t stream) {
    const float* x = (const float*)d_in[0];
    const int* pos = (const int*)d_in[1];  // row0 = src, row1 = dst
    const int* neg = (const int*)d_in[2];
    const float* W1 = (const float*)d_in[3];
    const float* b1 = (const float*)d_in[4];
    const float* W2 = (const float*)d_in[5];
    const float* b2 = (const float*)d_in[6];
    float* out = (float*)d_out;

    // workspace layout (bf16 intermediates)
    ushort16* A = (ushort16*)d_ws;                      // h1 [N,128]; later h2 [N,64]
    ushort16* B = A + (size_t)N_NODES * 128;            // z1 [N,128]; later z2 [N,64]
    float* dinv = (float*)(B + (size_t)N_NODES * 128);  // [N]
    int* hist = (int*)(dinv + N_NODES);                 // [N]
    int* rowstart = hist + N_NODES;                     // [N+1]
    int* cursor = rowstart + N_NODES + 1;               // [N]
    int* adj = cursor + N_NODES;                        // [N_POS]
    int* partials = adj + N_POS;                        // [128]
    ushort16* W1t = (ushort16*)(partials + 128);        // [128*128]
    ushort16* W2t = W1t + 128 * 128;                    // [64*128]

    const int* pos_src = pos;
    const int* pos_dst = pos + N_POS;

    constexpr int NB_SCAN = (N_NODES + 1023) / 1024;  // 98

    // ---- CSR build + dinv + weight transpose ----
    hipMemsetAsync(hist, 0, N_NODES * sizeof(int), stream);
    hist_count<<<(N_POS + 255) / 256, 256, 0, stream>>>(pos_dst, hist, N_POS);
    scan_reduce<<<NB_SCAN, 256, 0, stream>>>(hist, partials, N_NODES);
    scan_partials<<<1, 128, 0, stream>>>(partials, NB_SCAN);
    scan_final<<<NB_SCAN, 256, 0, stream>>>(hist, partials, rowstart, cursor, dinv, N_NODES);
    csr_fill<<<(N_POS + 255) / 256, 256, 0, stream>>>(pos_src, pos_dst, cursor, adj, N_POS);
    wt_convert<<<(128 * 128 + 64 * 128 + 255) / 256, 256, 0, stream>>>(W1, W2, W1t, W2t);

    // ---- layer 1 ----
    gemm_mfma<HIDDEN, false><<<(N_NODES + 63) / 64, 256, 0, stream>>>(x, W1t, A, N_NODES);
    agg_pull<HIDDEN, true><<<(N_NODES + 3) / 4, 256, 0, stream>>>(rowstart, adj, dinv, A, b1, B,
                                                                  N_NODES);

    // ---- layer 2 ----
    ushort16* h2 = A;  // [N,64]
    gemm_mfma<OUT_CH, true><<<(N_NODES + 63) / 64, 256, 0, stream>>>(B, W2t, h2, N_NODES);
    ushort16* z2 = B;  // [N,64]
    agg_pull<OUT_CH, false><<<(N_NODES + 3) / 4, 256, 0, stream>>>(rowstart, adj, dinv, h2, b2, z2,
                                                                   N_NODES);

    // ---- decode ----
    int edges_per_block = (256 / 64) * 4;  // 16
    decode_kernel<<<(N_POS + N_NEG + edges_per_block - 1) / edges_per_block, 256, 0, stream>>>(
        pos, neg, z2, out);
}

// Round 6
// 339.028 us; speedup vs baseline: 1.8437x; 1.1494x over previous
//
#include <hip/hip_runtime.h>

#define N_NODES 100000
#define IN_CH 128
#define HIDDEN 128
#define OUT_CH 64
#define N_POS 600000
#define N_NEG 600000

typedef unsigned int uint32;
typedef unsigned short ushort16;
typedef __attribute__((ext_vector_type(8))) short bf16x8;
typedef __attribute__((ext_vector_type(4))) float f32x4;

// ---- bf16 helpers ----
__device__ inline float bf_lo(uint32 u) {
    union { uint32 i; float f; } v;
    v.i = u << 16;
    return v.f;
}
__device__ inline float bf_hi(uint32 u) {
    union { uint32 i; float f; } v;
    v.i = u & 0xffff0000u;
    return v.f;
}
__device__ inline ushort16 f2bf(float f) {
    union { uint32 i; float f; } v;
    v.f = f;
    uint32 r = v.i + 0x7fffu + ((v.i >> 16) & 1u);  // round-to-nearest-even
    return (ushort16)(r >> 16);
}
__device__ inline uint32 pack2bf(float a, float b) {
    return (uint32)f2bf(a) | ((uint32)f2bf(b) << 16);
}

// ================= CSR build =================
__global__ void hist_count(const int* __restrict__ dst, int* __restrict__ hist, int n_edges) {
    int i = blockIdx.x * blockDim.x + threadIdx.x;
    if (i < n_edges) atomicAdd(&hist[dst[i]], 1);
}

__global__ void scan_reduce(const int* __restrict__ hist, int* __restrict__ partials, int n) {
    __shared__ int sdata[256];
    int b = blockIdx.x, t = threadIdx.x;
    int base = b * 1024;
    int s = 0;
    for (int i = t; i < 1024; i += 256) {
        int idx = base + i;
        s += (idx < n) ? hist[idx] : 0;
    }
    sdata[t] = s;
    __syncthreads();
    for (int off = 128; off > 0; off >>= 1) {
        if (t < off) sdata[t] += sdata[t + off];
        __syncthreads();
    }
    if (t == 0) partials[b] = sdata[0];
}

__global__ void scan_partials(int* __restrict__ partials, int nb) {
    __shared__ int tmp[128];
    int t = threadIdx.x;
    int v = (t < nb) ? partials[t] : 0;
    tmp[t] = v;
    __syncthreads();
    for (int off = 1; off < 128; off <<= 1) {
        int a = (t >= off) ? tmp[t - off] : 0;
        __syncthreads();
        tmp[t] += a;
        __syncthreads();
    }
    if (t < nb) partials[t] = tmp[t] - v;  // exclusive
}

__global__ void scan_final(const int* __restrict__ hist, const int* __restrict__ partials,
                           int* __restrict__ rowstart, int* __restrict__ cursor,
                           float* __restrict__ dinv, int n) {
    __shared__ int tsum[256];
    int t = threadIdx.x, b = blockIdx.x;
    int base = b * 1024 + t * 4;
    int v[4];
    int s = 0;
#pragma unroll
    for (int j = 0; j < 4; j++) {
        int i = base + j;
        v[j] = (i < n) ? hist[i] : 0;
        s += v[j];
    }
    tsum[t] = s;
    __syncthreads();
    for (int off = 1; off < 256; off <<= 1) {
        int a = (t >= off) ? tsum[t - off] : 0;
        __syncthreads();
        tsum[t] += a;
        __syncthreads();
    }
    int offset = partials[b] + (tsum[t] - s);
#pragma unroll
    for (int j = 0; j < 4; j++) {
        int i = base + j;
        if (i < n) {
            rowstart[i] = offset;
            cursor[i] = offset;
            dinv[i] = rsqrtf((float)v[j] + 1.0f);
            offset += v[j];
        }
    }
    if (b == 0 && t == 0) rowstart[n] = N_POS;
}

// fill adj + per-edge weight (dinv[src]*dinv[dst]) — removes the dependent
// dinv gather from the aggregation hot loop.
__global__ void csr_fill(const int* __restrict__ src, const int* __restrict__ dst,
                         const float* __restrict__ dinv, int* __restrict__ cursor,
                         int* __restrict__ adj, float* __restrict__ wgt, int n_edges) {
    int e = blockIdx.x * blockDim.x + threadIdx.x;
    if (e < n_edges) {
        int s = src[e], d = dst[e];
        int p = atomicAdd(&cursor[d], 1);
        adj[p] = s;
        wgt[p] = dinv[s] * dinv[d];
    }
}

// ===== one-shot: W1t[n][k]=bf16(W1[k][n]) (128x128), W2t[n][k]=bf16(W2[k][n]) (64x128) =====
__global__ void wt_convert(const float* __restrict__ W1, const float* __restrict__ W2,
                           ushort16* __restrict__ W1t, ushort16* __restrict__ W2t) {
    int i = blockIdx.x * blockDim.x + threadIdx.x;
    if (i < 128 * 128) {
        int n = i >> 7, k = i & 127;
        W1t[i] = f2bf(W1[k * 128 + n]);
    } else {
        int j = i - 128 * 128;
        if (j < 64 * 128) {
            int n = j >> 7, k = j & 127;
            W2t[j] = f2bf(W2[k * 64 + n]);
        }
    }
}

// ================= MFMA GEMM: H_bf16[n,M] = X[n,128] @ W[128,M] =================
template <int M, bool XBF>
__global__ __launch_bounds__(256) void gemm_mfma(const void* __restrict__ Xv,
                                                const ushort16* __restrict__ Wt,
                                                ushort16* __restrict__ H, int n) {
    constexpr int K = 128;
    constexpr int TN = 64;
    constexpr int XS = 136;  // padded LDS row stride (shorts)
    __shared__ short Xs[TN * XS];
    __shared__ short Ws[M * XS];
    int tid = threadIdx.x;
    int node0 = blockIdx.x * TN;

    for (int q = tid; q < M * K / 8; q += 256) {
        int row = q >> 4;
        int c = q & 15;
        uint4 v = ((const uint4*)Wt)[q];
        *(uint4*)(Ws + row * XS + c * 8) = v;
    }
    if (!XBF) {
        const float* X = (const float*)Xv;
        int row = tid >> 2, part = tid & 3;
        int gn = node0 + row;
#pragma unroll
        for (int c = 0; c < 8; ++c) {
            int k = part * 32 + c * 4;
            float4 v = (gn < n) ? *(const float4*)(X + (size_t)gn * K + k) : float4{0, 0, 0, 0};
            uint2 p = {pack2bf(v.x, v.y), pack2bf(v.z, v.w)};
            *(uint2*)(Xs + row * XS + k) = p;
        }
    } else {
        const ushort16* X = (const ushort16*)Xv;
        for (int q = tid; q < TN * K / 8; q += 256) {
            int row = q >> 4;
            int c = q & 15;
            int gn = node0 + row;
            uint4 v = (gn < n) ? ((const uint4*)(X + (size_t)gn * K))[c] : uint4{0, 0, 0, 0};
            *(uint4*)(Xs + row * XS + c * 8) = v;
        }
    }
    __syncthreads();

    constexpr int CT = M / 16;
    int w = tid >> 6;
    int lane = tid & 63;
    int l15 = lane & 15;
    int quad = lane >> 4;

    f32x4 acc[CT] = {};
    const short* xrow = Xs + (w * 16 + l15) * XS + quad * 8;
#pragma unroll
    for (int kk = 0; kk < 4; ++kk) {
        bf16x8 a = *(const bf16x8*)(xrow + kk * 32);
#pragma unroll
        for (int ct = 0; ct < CT; ++ct) {
            bf16x8 b = *(const bf16x8*)(Ws + (ct * 16 + l15) * XS + quad * 8 + kk * 32);
            acc[ct] = __builtin_amdgcn_mfma_f32_16x16x32_bf16(a, b, acc[ct], 0, 0, 0);
        }
    }

#pragma unroll
    for (int ct = 0; ct < CT; ++ct) {
#pragma unroll
        for (int r = 0; r < 4; ++r) {
            int gn = node0 + w * 16 + quad * 4 + r;
            if (gn < n) H[(size_t)gn * M + ct * 16 + l15] = f2bf(acc[ct][r]);
        }
    }
}

// ========= fused pull aggregation + self-loop + bias (+relu), bf16 H/Z =========
// one wave per node; 4-way unrolled neighbor loop, 4 independent accumulators,
// per-edge weights precomputed -> load chain is adj[p] -> H row only.
template <int F, bool RELU>
__global__ void agg_pull(const int* __restrict__ rowstart, const int* __restrict__ adj,
                         const float* __restrict__ wgt, const float* __restrict__ dinv,
                         const ushort16* __restrict__ H, const float* __restrict__ bias,
                         ushort16* __restrict__ Z, int n) {
    int wave = threadIdx.x >> 6;
    int lane = threadIdx.x & 63;
    int node = blockIdx.x * (blockDim.x >> 6) + wave;
    if (node >= n) return;
    float dn = dinv[node];
    int rs = rowstart[node], re = rowstart[node + 1];
    if (F == 128) {
        float ax0 = 0, ay0 = 0, ax1 = 0, ay1 = 0, ax2 = 0, ay2 = 0, ax3 = 0, ay3 = 0;
        int p = rs;
        for (; p + 4 <= re; p += 4) {
            int s0 = adj[p], s1 = adj[p + 1], s2 = adj[p + 2], s3 = adj[p + 3];
            float w0 = wgt[p], w1 = wgt[p + 1], w2 = wgt[p + 2], w3 = wgt[p + 3];
            uint32 h0 = *(const uint32*)(H + (size_t)s0 * F + lane * 2);
            uint32 h1 = *(const uint32*)(H + (size_t)s1 * F + lane * 2);
            uint32 h2 = *(const uint32*)(H + (size_t)s2 * F + lane * 2);
            uint32 h3 = *(const uint32*)(H + (size_t)s3 * F + lane * 2);
            ax0 += bf_lo(h0) * w0; ay0 += bf_hi(h0) * w0;
            ax1 += bf_lo(h1) * w1; ay1 += bf_hi(h1) * w1;
            ax2 += bf_lo(h2) * w2; ay2 += bf_hi(h2) * w2;
            ax3 += bf_lo(h3) * w3; ay3 += bf_hi(h3) * w3;
        }
        for (; p < re; ++p) {
            int s = adj[p];
            float w = wgt[p];
            uint32 h = *(const uint32*)(H + (size_t)s * F + lane * 2);
            ax0 += bf_lo(h) * w;
            ay0 += bf_hi(h) * w;
        }
        float ax = (ax0 + ax1) + (ax2 + ax3);
        float ay = (ay0 + ay1) + (ay2 + ay3);
        uint32 hv = *(const uint32*)(H + (size_t)node * F + lane * 2);
        float2 bv = *(const float2*)(bias + lane * 2);
        float vx = ax + bf_lo(hv) * dn * dn + bv.x;
        float vy = ay + bf_hi(hv) * dn * dn + bv.y;
        if (RELU) {
            vx = fmaxf(vx, 0.0f);
            vy = fmaxf(vy, 0.0f);
        }
        *(uint32*)(Z + (size_t)node * F + lane * 2) = pack2bf(vx, vy);
    } else {  // F == 64
        float a0 = 0, a1 = 0, a2 = 0, a3 = 0;
        int p = rs;
        for (; p + 4 <= re; p += 4) {
            int s0 = adj[p], s1 = adj[p + 1], s2 = adj[p + 2], s3 = adj[p + 3];
            float w0 = wgt[p], w1 = wgt[p + 1], w2 = wgt[p + 2], w3 = wgt[p + 3];
            float h0 = bf_lo((uint32)H[(size_t)s0 * F + lane]);
            float h1 = bf_lo((uint32)H[(size_t)s1 * F + lane]);
            float h2 = bf_lo((uint32)H[(size_t)s2 * F + lane]);
            float h3 = bf_lo((uint32)H[(size_t)s3 * F + lane]);
            a0 += h0 * w0;
            a1 += h1 * w1;
            a2 += h2 * w2;
            a3 += h3 * w3;
        }
        for (; p < re; ++p) {
            a0 += bf_lo((uint32)H[(size_t)adj[p] * F + lane]) * wgt[p];
        }
        float acc = (a0 + a1) + (a2 + a3);
        float h = bf_lo((uint32)H[(size_t)node * F + lane]);
        float v = acc + h * dn * dn + bias[lane];
        if (RELU) v = fmaxf(v, 0.0f);
        Z[(size_t)node * F + lane] = f2bf(v);
    }
}

// ===== decode: 16 lanes per edge, bf16 rows; one line-fetch per row =====
__global__ void decode_kernel(const int* __restrict__ pos, const int* __restrict__ neg,
                              const ushort16* __restrict__ Z, float* __restrict__ out) {
    int wid = threadIdx.x >> 6;
    int lane = threadIdx.x & 63;
    int g = lane >> 4;
    int l = lane & 15;
    int e = (blockIdx.x * (blockDim.x >> 6) + wid) * 4 + g;
    if (e >= N_POS + N_NEG) return;
    int a, b;
    if (e < N_POS) {
        a = pos[e];
        b = pos[N_POS + e];
    } else {
        int e2 = e - N_POS;
        a = neg[e2];
        b = neg[N_NEG + e2];
    }
    uint2 ua = *(const uint2*)(Z + (size_t)a * OUT_CH + l * 4);
    uint2 ub = *(const uint2*)(Z + (size_t)b * OUT_CH + l * 4);
    float acc = bf_lo(ua.x) * bf_lo(ub.x) + bf_hi(ua.x) * bf_hi(ub.x) +
                bf_lo(ua.y) * bf_lo(ub.y) + bf_hi(ua.y) * bf_hi(ub.y);
#pragma unroll
    for (int off = 8; off > 0; off >>= 1) acc += __shfl_down(acc, off, 16);
    if (l == 0) out[e] = acc;
}

extern "C" void kernel_launch(void* const* d_in, const int* in_sizes, int n_in,
                              void* d_out, int out_size, void* d_ws, size_t ws_size,
                              hipStream_t stream) {
    const float* x = (const float*)d_in[0];
    const int* pos = (const int*)d_in[1];  // row0 = src, row1 = dst
    const int* neg = (const int*)d_in[2];
    const float* W1 = (const float*)d_in[3];
    const float* b1 = (const float*)d_in[4];
    const float* W2 = (const float*)d_in[5];
    const float* b2 = (const float*)d_in[6];
    float* out = (float*)d_out;

    // workspace layout (bf16 intermediates)
    ushort16* A = (ushort16*)d_ws;                      // h1 [N,128]; later h2 [N,64]
    ushort16* B = A + (size_t)N_NODES * 128;            // z1 [N,128]; later z2 [N,64]
    float* dinv = (float*)(B + (size_t)N_NODES * 128);  // [N]
    int* hist = (int*)(dinv + N_NODES);                 // [N]
    int* rowstart = hist + N_NODES;                     // [N+1]
    int* cursor = rowstart + N_NODES + 1;               // [N]
    int* adj = cursor + N_NODES;                        // [N_POS]
    float* wgt = (float*)(adj + N_POS);                 // [N_POS]
    int* partials = (int*)(wgt + N_POS);                // [128]
    ushort16* W1t = (ushort16*)(partials + 128);        // [128*128]
    ushort16* W2t = W1t + 128 * 128;                    // [64*128]

    const int* pos_src = pos;
    const int* pos_dst = pos + N_POS;

    constexpr int NB_SCAN = (N_NODES + 1023) / 1024;  // 98

    // ---- CSR build + dinv + weight transpose ----
    hipMemsetAsync(hist, 0, N_NODES * sizeof(int), stream);
    hist_count<<<(N_POS + 255) / 256, 256, 0, stream>>>(pos_dst, hist, N_POS);
    scan_reduce<<<NB_SCAN, 256, 0, stream>>>(hist, partials, N_NODES);
    scan_partials<<<1, 128, 0, stream>>>(partials, NB_SCAN);
    scan_final<<<NB_SCAN, 256, 0, stream>>>(hist, partials, rowstart, cursor, dinv, N_NODES);
    csr_fill<<<(N_POS + 255) / 256, 256, 0, stream>>>(pos_src, pos_dst, dinv, cursor, adj, wgt,
                                                      N_POS);
    wt_convert<<<(128 * 128 + 64 * 128 + 255) / 256, 256, 0, stream>>>(W1, W2, W1t, W2t);

    // ---- layer 1 ----
    gemm_mfma<HIDDEN, false><<<(N_NODES + 63) / 64, 256, 0, stream>>>(x, W1t, A, N_NODES);
    agg_pull<HIDDEN, true><<<(N_NODES + 3) / 4, 256, 0, stream>>>(rowstart, adj, wgt, dinv, A, b1,
                                                                  B, N_NODES);

    // ---- layer 2 ----
    ushort16* h2 = A;  // [N,64]
    gemm_mfma<OUT_CH, true><<<(N_NODES + 63) / 64, 256, 0, stream>>>(B, W2t, h2, N_NODES);
    ushort16* z2 = B;  // [N,64]
    agg_pull<OUT_CH, false><<<(N_NODES + 3) / 4, 256, 0, stream>>>(rowstart, adj, wgt, dinv, h2,
                                                                   b2, z2, N_NODES);

    // ---- decode ----
    int edges_per_block = (256 / 64) * 4;  // 16
    decode_kernel<<<(N_POS + N_NEG + edges_per_block - 1) / edges_per_block, 256, 0, stream>>>(
        pos, neg, z2, out);
}

// Round 7
// 304.021 us; speedup vs baseline: 2.0560x; 1.1151x over previous
//
#include <hip/hip_runtime.h>

#define N_NODES 100000
#define IN_CH 128
#define HIDDEN 128
#define OUT_CH 64
#define N_POS 600000
#define N_NEG 600000

typedef unsigned int uint32;
typedef unsigned short ushort16;
typedef __attribute__((ext_vector_type(8))) short bf16x8;
typedef __attribute__((ext_vector_type(4))) float f32x4;

// ---- bf16 helpers ----
__device__ inline float bf_lo(uint32 u) {
    union { uint32 i; float f; } v;
    v.i = u << 16;
    return v.f;
}
__device__ inline float bf_hi(uint32 u) {
    union { uint32 i; float f; } v;
    v.i = u & 0xffff0000u;
    return v.f;
}
__device__ inline ushort16 f2bf(float f) {
    union { uint32 i; float f; } v;
    v.f = f;
    uint32 r = v.i + 0x7fffu + ((v.i >> 16) & 1u);  // round-to-nearest-even
    return (ushort16)(r >> 16);
}
__device__ inline uint32 pack2bf(float a, float b) {
    return (uint32)f2bf(a) | ((uint32)f2bf(b) << 16);
}

// ================= CSR build =================
__global__ void hist_count(const int* __restrict__ dst, int* __restrict__ hist, int n_edges) {
    int i = blockIdx.x * blockDim.x + threadIdx.x;
    if (i < n_edges) atomicAdd(&hist[dst[i]], 1);
}

__global__ void scan_reduce(const int* __restrict__ hist, int* __restrict__ partials, int n) {
    __shared__ int sdata[256];
    int b = blockIdx.x, t = threadIdx.x;
    int base = b * 1024;
    int s = 0;
    for (int i = t; i < 1024; i += 256) {
        int idx = base + i;
        s += (idx < n) ? hist[idx] : 0;
    }
    sdata[t] = s;
    __syncthreads();
    for (int off = 128; off > 0; off >>= 1) {
        if (t < off) sdata[t] += sdata[t + off];
        __syncthreads();
    }
    if (t == 0) partials[b] = sdata[0];
}

__global__ void scan_partials(int* __restrict__ partials, int nb) {
    __shared__ int tmp[128];
    int t = threadIdx.x;
    int v = (t < nb) ? partials[t] : 0;
    tmp[t] = v;
    __syncthreads();
    for (int off = 1; off < 128; off <<= 1) {
        int a = (t >= off) ? tmp[t - off] : 0;
        __syncthreads();
        tmp[t] += a;
        __syncthreads();
    }
    if (t < nb) partials[t] = tmp[t] - v;  // exclusive
}

__global__ void scan_final(const int* __restrict__ hist, const int* __restrict__ partials,
                           int* __restrict__ rowstart, int* __restrict__ cursor,
                           float* __restrict__ dinv, int n) {
    __shared__ int tsum[256];
    int t = threadIdx.x, b = blockIdx.x;
    int base = b * 1024 + t * 4;
    int v[4];
    int s = 0;
#pragma unroll
    for (int j = 0; j < 4; j++) {
        int i = base + j;
        v[j] = (i < n) ? hist[i] : 0;
        s += v[j];
    }
    tsum[t] = s;
    __syncthreads();
    for (int off = 1; off < 256; off <<= 1) {
        int a = (t >= off) ? tsum[t - off] : 0;
        __syncthreads();
        tsum[t] += a;
        __syncthreads();
    }
    int offset = partials[b] + (tsum[t] - s);
#pragma unroll
    for (int j = 0; j < 4; j++) {
        int i = base + j;
        if (i < n) {
            rowstart[i] = offset;
            cursor[i] = offset;
            dinv[i] = rsqrtf((float)v[j] + 1.0f);
            offset += v[j];
        }
    }
    if (b == 0 && t == 0) rowstart[n] = N_POS;
}

__global__ void csr_fill(const int* __restrict__ src, const int* __restrict__ dst,
                         const float* __restrict__ dinv, int* __restrict__ cursor,
                         int* __restrict__ adj, float* __restrict__ wgt, int n_edges) {
    int e = blockIdx.x * blockDim.x + threadIdx.x;
    if (e < n_edges) {
        int s = src[e], d = dst[e];
        int p = atomicAdd(&cursor[d], 1);
        adj[p] = s;
        wgt[p] = dinv[s] * dinv[d];
    }
}

// ===== one-shot: W1t[n][k]=bf16(W1[k][n]) (128x128), W2t[n][k]=bf16(W2[k][n]) (64x128) =====
__global__ void wt_convert(const float* __restrict__ W1, const float* __restrict__ W2,
                           ushort16* __restrict__ W1t, ushort16* __restrict__ W2t) {
    int i = blockIdx.x * blockDim.x + threadIdx.x;
    if (i < 128 * 128) {
        int n = i >> 7, k = i & 127;
        W1t[i] = f2bf(W1[k * 128 + n]);
    } else {
        int j = i - 128 * 128;
        if (j < 64 * 128) {
            int n = j >> 7, k = j & 127;
            W2t[j] = f2bf(W2[k * 64 + n]);
        }
    }
}

// ================= MFMA GEMM: H_bf16[n,M] = X[n,128] @ W[128,M] =================
template <int M, bool XBF>
__global__ __launch_bounds__(256) void gemm_mfma(const void* __restrict__ Xv,
                                                const ushort16* __restrict__ Wt,
                                                ushort16* __restrict__ H, int n) {
    constexpr int K = 128;
    constexpr int TN = 64;
    constexpr int XS = 136;  // padded LDS row stride (shorts)
    __shared__ short Xs[TN * XS];
    __shared__ short Ws[M * XS];
    int tid = threadIdx.x;
    int node0 = blockIdx.x * TN;

    for (int q = tid; q < M * K / 8; q += 256) {
        int row = q >> 4;
        int c = q & 15;
        uint4 v = ((const uint4*)Wt)[q];
        *(uint4*)(Ws + row * XS + c * 8) = v;
    }
    if (!XBF) {
        const float* X = (const float*)Xv;
        int row = tid >> 2, part = tid & 3;
        int gn = node0 + row;
#pragma unroll
        for (int c = 0; c < 8; ++c) {
            int k = part * 32 + c * 4;
            float4 v = (gn < n) ? *(const float4*)(X + (size_t)gn * K + k) : float4{0, 0, 0, 0};
            uint2 p = {pack2bf(v.x, v.y), pack2bf(v.z, v.w)};
            *(uint2*)(Xs + row * XS + k) = p;
        }
    } else {
        const ushort16* X = (const ushort16*)Xv;
        for (int q = tid; q < TN * K / 8; q += 256) {
            int row = q >> 4;
            int c = q & 15;
            int gn = node0 + row;
            uint4 v = (gn < n) ? ((const uint4*)(X + (size_t)gn * K))[c] : uint4{0, 0, 0, 0};
            *(uint4*)(Xs + row * XS + c * 8) = v;
        }
    }
    __syncthreads();

    constexpr int CT = M / 16;
    int w = tid >> 6;
    int lane = tid & 63;
    int l15 = lane & 15;
    int quad = lane >> 4;

    f32x4 acc[CT] = {};
    const short* xrow = Xs + (w * 16 + l15) * XS + quad * 8;
#pragma unroll
    for (int kk = 0; kk < 4; ++kk) {
        bf16x8 a = *(const bf16x8*)(xrow + kk * 32);
#pragma unroll
        for (int ct = 0; ct < CT; ++ct) {
            bf16x8 b = *(const bf16x8*)(Ws + (ct * 16 + l15) * XS + quad * 8 + kk * 32);
            acc[ct] = __builtin_amdgcn_mfma_f32_16x16x32_bf16(a, b, acc[ct], 0, 0, 0);
        }
    }

#pragma unroll
    for (int ct = 0; ct < CT; ++ct) {
#pragma unroll
        for (int r = 0; r < 4; ++r) {
            int gn = node0 + w * 16 + quad * 4 + r;
            if (gn < n) H[(size_t)gn * M + ct * 16 + l15] = f2bf(acc[ct][r]);
        }
    }
}

// ========= fused pull aggregation + self-loop + bias (+relu), bf16 H/Z =========
// TWO nodes per wave (32 lanes each) -> each load instruction fetches neighbor
// rows for two nodes; 4-way unroll -> up to 8 gathers in flight per wave.
template <int F, bool RELU>
__global__ void agg_pull(const int* __restrict__ rowstart, const int* __restrict__ adj,
                         const float* __restrict__ wgt, const float* __restrict__ dinv,
                         const ushort16* __restrict__ H, const float* __restrict__ bias,
                         ushort16* __restrict__ Z, int n) {
    int g = threadIdx.x >> 5;  // 32-lane group
    int l = threadIdx.x & 31;
    int node = blockIdx.x * (blockDim.x >> 5) + g;
    if (node >= n) return;
    float dn = dinv[node];
    int rs = rowstart[node], re = rowstart[node + 1];
    if (F == 128) {
        // lane covers elements l*4 .. l*4+3 (8B)
        float ac[4][4] = {};
        int p = rs;
        for (; p + 4 <= re; p += 4) {
            int s0 = adj[p], s1 = adj[p + 1], s2 = adj[p + 2], s3 = adj[p + 3];
            float w0 = wgt[p], w1 = wgt[p + 1], w2 = wgt[p + 2], w3 = wgt[p + 3];
            uint2 h0 = *(const uint2*)(H + (size_t)s0 * F + l * 4);
            uint2 h1 = *(const uint2*)(H + (size_t)s1 * F + l * 4);
            uint2 h2 = *(const uint2*)(H + (size_t)s2 * F + l * 4);
            uint2 h3 = *(const uint2*)(H + (size_t)s3 * F + l * 4);
            ac[0][0] += bf_lo(h0.x) * w0; ac[0][1] += bf_hi(h0.x) * w0;
            ac[0][2] += bf_lo(h0.y) * w0; ac[0][3] += bf_hi(h0.y) * w0;
            ac[1][0] += bf_lo(h1.x) * w1; ac[1][1] += bf_hi(h1.x) * w1;
            ac[1][2] += bf_lo(h1.y) * w1; ac[1][3] += bf_hi(h1.y) * w1;
            ac[2][0] += bf_lo(h2.x) * w2; ac[2][1] += bf_hi(h2.x) * w2;
            ac[2][2] += bf_lo(h2.y) * w2; ac[2][3] += bf_hi(h2.y) * w2;
            ac[3][0] += bf_lo(h3.x) * w3; ac[3][1] += bf_hi(h3.x) * w3;
            ac[3][2] += bf_lo(h3.y) * w3; ac[3][3] += bf_hi(h3.y) * w3;
        }
        for (; p < re; ++p) {
            int s = adj[p];
            float w = wgt[p];
            uint2 h = *(const uint2*)(H + (size_t)s * F + l * 4);
            ac[0][0] += bf_lo(h.x) * w; ac[0][1] += bf_hi(h.x) * w;
            ac[0][2] += bf_lo(h.y) * w; ac[0][3] += bf_hi(h.y) * w;
        }
        uint2 hv = *(const uint2*)(H + (size_t)node * F + l * 4);
        float4 bv = *(const float4*)(bias + l * 4);
        float d2 = dn * dn;
        float v0 = (ac[0][0] + ac[1][0]) + (ac[2][0] + ac[3][0]) + bf_lo(hv.x) * d2 + bv.x;
        float v1 = (ac[0][1] + ac[1][1]) + (ac[2][1] + ac[3][1]) + bf_hi(hv.x) * d2 + bv.y;
        float v2 = (ac[0][2] + ac[1][2]) + (ac[2][2] + ac[3][2]) + bf_lo(hv.y) * d2 + bv.z;
        float v3 = (ac[0][3] + ac[1][3]) + (ac[2][3] + ac[3][3]) + bf_hi(hv.y) * d2 + bv.w;
        if (RELU) {
            v0 = fmaxf(v0, 0.0f); v1 = fmaxf(v1, 0.0f);
            v2 = fmaxf(v2, 0.0f); v3 = fmaxf(v3, 0.0f);
        }
        *(uint2*)(Z + (size_t)node * F + l * 4) = uint2{pack2bf(v0, v1), pack2bf(v2, v3)};
    } else {  // F == 64: lane covers elements l*2, l*2+1 (4B)
        float ax0 = 0, ay0 = 0, ax1 = 0, ay1 = 0, ax2 = 0, ay2 = 0, ax3 = 0, ay3 = 0;
        int p = rs;
        for (; p + 4 <= re; p += 4) {
            int s0 = adj[p], s1 = adj[p + 1], s2 = adj[p + 2], s3 = adj[p + 3];
            float w0 = wgt[p], w1 = wgt[p + 1], w2 = wgt[p + 2], w3 = wgt[p + 3];
            uint32 h0 = *(const uint32*)(H + (size_t)s0 * F + l * 2);
            uint32 h1 = *(const uint32*)(H + (size_t)s1 * F + l * 2);
            uint32 h2 = *(const uint32*)(H + (size_t)s2 * F + l * 2);
            uint32 h3 = *(const uint32*)(H + (size_t)s3 * F + l * 2);
            ax0 += bf_lo(h0) * w0; ay0 += bf_hi(h0) * w0;
            ax1 += bf_lo(h1) * w1; ay1 += bf_hi(h1) * w1;
            ax2 += bf_lo(h2) * w2; ay2 += bf_hi(h2) * w2;
            ax3 += bf_lo(h3) * w3; ay3 += bf_hi(h3) * w3;
        }
        for (; p < re; ++p) {
            int s = adj[p];
            float w = wgt[p];
            uint32 h = *(const uint32*)(H + (size_t)s * F + l * 2);
            ax0 += bf_lo(h) * w;
            ay0 += bf_hi(h) * w;
        }
        float ax = (ax0 + ax1) + (ax2 + ax3);
        float ay = (ay0 + ay1) + (ay2 + ay3);
        uint32 hv = *(const uint32*)(H + (size_t)node * F + l * 2);
        float2 bv = *(const float2*)(bias + l * 2);
        float d2 = dn * dn;
        float vx = ax + bf_lo(hv) * d2 + bv.x;
        float vy = ay + bf_hi(hv) * d2 + bv.y;
        if (RELU) {
            vx = fmaxf(vx, 0.0f);
            vy = fmaxf(vy, 0.0f);
        }
        *(uint32*)(Z + (size_t)node * F + l * 2) = pack2bf(vx, vy);
    }
}

// ===== decode via MFMA: 16 edges per wave =====
// A-frag: lane l15 holds row Z[a[l15]], k-slice quad*8 (+32 for 2nd mfma).
// B-frag: lane l15 holds row Z[b[l15]], same k-slices.
// C[m][n] = dot(Za_m, Zb_n); diagonal (m==n) is the output.
// N_POS % 16 == 0, so each wave is uniformly pos or neg.
__global__ void decode_mfma(const int* __restrict__ pos, const int* __restrict__ neg,
                            const short* __restrict__ Z, float* __restrict__ out) {
    int wid = threadIdx.x >> 6;
    int lane = threadIdx.x & 63;
    int l15 = lane & 15;
    int quad = lane >> 4;
    int e0 = (blockIdx.x * 4 + wid) * 16;
    if (e0 >= N_POS + N_NEG) return;
    const int* bp = (e0 < N_POS) ? pos : (neg - N_POS);
    int e = e0 + l15;
    int a = bp[e];
    int b = bp[600000 + e];  // N_POS == N_NEG == 600000

    const short* za = Z + (size_t)a * OUT_CH + quad * 8;
    const short* zb = Z + (size_t)b * OUT_CH + quad * 8;
    bf16x8 a0 = *(const bf16x8*)(za);
    bf16x8 a1 = *(const bf16x8*)(za + 32);
    bf16x8 b0 = *(const bf16x8*)(zb);
    bf16x8 b1 = *(const bf16x8*)(zb + 32);

    f32x4 acc = {};
    acc = __builtin_amdgcn_mfma_f32_16x16x32_bf16(a0, b0, acc, 0, 0, 0);
    acc = __builtin_amdgcn_mfma_f32_16x16x32_bf16(a1, b1, acc, 0, 0, 0);

    if (quad == (l15 >> 2)) out[e] = acc[l15 & 3];
}

extern "C" void kernel_launch(void* const* d_in, const int* in_sizes, int n_in,
                              void* d_out, int out_size, void* d_ws, size_t ws_size,
                              hipStream_t stream) {
    const float* x = (const float*)d_in[0];
    const int* pos = (const int*)d_in[1];  // row0 = src, row1 = dst
    const int* neg = (const int*)d_in[2];
    const float* W1 = (const float*)d_in[3];
    const float* b1 = (const float*)d_in[4];
    const float* W2 = (const float*)d_in[5];
    const float* b2 = (const float*)d_in[6];
    float* out = (float*)d_out;

    // workspace layout (bf16 intermediates)
    ushort16* A = (ushort16*)d_ws;                      // h1 [N,128]; later h2 [N,64]
    ushort16* B = A + (size_t)N_NODES * 128;            // z1 [N,128]; later z2 [N,64]
    float* dinv = (float*)(B + (size_t)N_NODES * 128);  // [N]
    int* hist = (int*)(dinv + N_NODES);                 // [N]
    int* rowstart = hist + N_NODES;                     // [N+1]
    int* cursor = rowstart + N_NODES + 1;               // [N]
    int* adj = cursor + N_NODES;                        // [N_POS]
    float* wgt = (float*)(adj + N_POS);                 // [N_POS]
    int* partials = (int*)(wgt + N_POS);                // [128]
    ushort16* W1t = (ushort16*)(partials + 128);        // [128*128]
    ushort16* W2t = W1t + 128 * 128;                    // [64*128]

    const int* pos_src = pos;
    const int* pos_dst = pos + N_POS;

    constexpr int NB_SCAN = (N_NODES + 1023) / 1024;  // 98

    // ---- CSR build + dinv + weight transpose ----
    hipMemsetAsync(hist, 0, N_NODES * sizeof(int), stream);
    hist_count<<<(N_POS + 255) / 256, 256, 0, stream>>>(pos_dst, hist, N_POS);
    scan_reduce<<<NB_SCAN, 256, 0, stream>>>(hist, partials, N_NODES);
    scan_partials<<<1, 128, 0, stream>>>(partials, NB_SCAN);
    scan_final<<<NB_SCAN, 256, 0, stream>>>(hist, partials, rowstart, cursor, dinv, N_NODES);
    csr_fill<<<(N_POS + 255) / 256, 256, 0, stream>>>(pos_src, pos_dst, dinv, cursor, adj, wgt,
                                                      N_POS);
    wt_convert<<<(128 * 128 + 64 * 128 + 255) / 256, 256, 0, stream>>>(W1, W2, W1t, W2t);

    // ---- layer 1 ----
    gemm_mfma<HIDDEN, false><<<(N_NODES + 63) / 64, 256, 0, stream>>>(x, W1t, A, N_NODES);
    agg_pull<HIDDEN, true><<<(N_NODES + 7) / 8, 256, 0, stream>>>(rowstart, adj, wgt, dinv, A, b1,
                                                                  B, N_NODES);

    // ---- layer 2 ----
    ushort16* h2 = A;  // [N,64]
    gemm_mfma<OUT_CH, true><<<(N_NODES + 63) / 64, 256, 0, stream>>>(B, W2t, h2, N_NODES);
    ushort16* z2 = B;  // [N,64]
    agg_pull<OUT_CH, false><<<(N_NODES + 7) / 8, 256, 0, stream>>>(rowstart, adj, wgt, dinv, h2,
                                                                   b2, z2, N_NODES);

    // ---- decode (16 edges/wave, 64/block) ----
    decode_mfma<<<(N_POS + N_NEG) / 64, 256, 0, stream>>>(pos, neg, (const short*)z2, out);
}

// Round 8
// 289.604 us; speedup vs baseline: 2.1584x; 1.0498x over previous
//
#include <hip/hip_runtime.h>

#define N_NODES 100000
#define IN_CH 128
#define HIDDEN 128
#define OUT_CH 64
#define N_POS 600000
#define N_NEG 600000

typedef unsigned int uint32;
typedef unsigned short ushort16;
typedef __attribute__((ext_vector_type(8))) short bf16x8;
typedef __attribute__((ext_vector_type(4))) float f32x4;

// ---- bf16 helpers ----
__device__ inline float bf_lo(uint32 u) {
    union { uint32 i; float f; } v;
    v.i = u << 16;
    return v.f;
}
__device__ inline float bf_hi(uint32 u) {
    union { uint32 i; float f; } v;
    v.i = u & 0xffff0000u;
    return v.f;
}
__device__ inline ushort16 f2bf(float f) {
    union { uint32 i; float f; } v;
    v.f = f;
    uint32 r = v.i + 0x7fffu + ((v.i >> 16) & 1u);  // round-to-nearest-even
    return (ushort16)(r >> 16);
}
__device__ inline uint32 pack2bf(float a, float b) {
    return (uint32)f2bf(a) | ((uint32)f2bf(b) << 16);
}

// ================= CSR build =================
__global__ void hist_count(const int* __restrict__ dst, int* __restrict__ hist, int n_edges) {
    int i = blockIdx.x * blockDim.x + threadIdx.x;
    if (i < n_edges) atomicAdd(&hist[dst[i]], 1);
}

__global__ void scan_reduce(const int* __restrict__ hist, int* __restrict__ partials, int n) {
    __shared__ int sdata[256];
    int b = blockIdx.x, t = threadIdx.x;
    int base = b * 1024;
    int s = 0;
    for (int i = t; i < 1024; i += 256) {
        int idx = base + i;
        s += (idx < n) ? hist[idx] : 0;
    }
    sdata[t] = s;
    __syncthreads();
    for (int off = 128; off > 0; off >>= 1) {
        if (t < off) sdata[t] += sdata[t + off];
        __syncthreads();
    }
    if (t == 0) partials[b] = sdata[0];
}

__global__ void scan_partials(int* __restrict__ partials, int nb) {
    __shared__ int tmp[128];
    int t = threadIdx.x;
    int v = (t < nb) ? partials[t] : 0;
    tmp[t] = v;
    __syncthreads();
    for (int off = 1; off < 128; off <<= 1) {
        int a = (t >= off) ? tmp[t - off] : 0;
        __syncthreads();
        tmp[t] += a;
        __syncthreads();
    }
    if (t < nb) partials[t] = tmp[t] - v;  // exclusive
}

__global__ void scan_final(const int* __restrict__ hist, const int* __restrict__ partials,
                           int* __restrict__ rowstart, int* __restrict__ cursor,
                           float* __restrict__ dinv, int n) {
    __shared__ int tsum[256];
    int t = threadIdx.x, b = blockIdx.x;
    int base = b * 1024 + t * 4;
    int v[4];
    int s = 0;
#pragma unroll
    for (int j = 0; j < 4; j++) {
        int i = base + j;
        v[j] = (i < n) ? hist[i] : 0;
        s += v[j];
    }
    tsum[t] = s;
    __syncthreads();
    for (int off = 1; off < 256; off <<= 1) {
        int a = (t >= off) ? tsum[t - off] : 0;
        __syncthreads();
        tsum[t] += a;
        __syncthreads();
    }
    int offset = partials[b] + (tsum[t] - s);
#pragma unroll
    for (int j = 0; j < 4; j++) {
        int i = base + j;
        if (i < n) {
            rowstart[i] = offset;
            cursor[i] = offset;
            dinv[i] = rsqrtf((float)v[j] + 1.0f);
            offset += v[j];
        }
    }
    if (b == 0 && t == 0) rowstart[n] = N_POS;
}

// adj+wgt packed into int2: one 8B scattered store per edge (vs two 4B)
__global__ void csr_fill(const int* __restrict__ src, const int* __restrict__ dst,
                         const float* __restrict__ dinv, int* __restrict__ cursor,
                         int2* __restrict__ adjw, int n_edges) {
    int e = blockIdx.x * blockDim.x + threadIdx.x;
    if (e < n_edges) {
        int s = src[e], d = dst[e];
        int p = atomicAdd(&cursor[d], 1);
        adjw[p] = int2{s, __float_as_int(dinv[s] * dinv[d])};
    }
}

// ===== one-shot: W1t[n][k]=bf16(W1[k][n]) (128x128), W2t[n][k]=bf16(W2[k][n]) (64x128) =====
__global__ void wt_convert(const float* __restrict__ W1, const float* __restrict__ W2,
                           ushort16* __restrict__ W1t, ushort16* __restrict__ W2t) {
    int i = blockIdx.x * blockDim.x + threadIdx.x;
    if (i < 128 * 128) {
        int n = i >> 7, k = i & 127;
        W1t[i] = f2bf(W1[k * 128 + n]);
    } else {
        int j = i - 128 * 128;
        if (j < 64 * 128) {
            int n = j >> 7, k = j & 127;
            W2t[j] = f2bf(W2[k * 64 + n]);
        }
    }
}

// ================= MFMA GEMM: H_bf16[n,M] = X[n,128] @ W[128,M] =================
template <int M, bool XBF>
__global__ __launch_bounds__(256) void gemm_mfma(const void* __restrict__ Xv,
                                                const ushort16* __restrict__ Wt,
                                                ushort16* __restrict__ H, int n) {
    constexpr int K = 128;
    constexpr int TN = 64;
    constexpr int XS = 136;  // padded LDS row stride (shorts)
    __shared__ short Xs[TN * XS];
    __shared__ short Ws[M * XS];
    int tid = threadIdx.x;
    int node0 = blockIdx.x * TN;

    for (int q = tid; q < M * K / 8; q += 256) {
        int row = q >> 4;
        int c = q & 15;
        uint4 v = ((const uint4*)Wt)[q];
        *(uint4*)(Ws + row * XS + c * 8) = v;
    }
    if (!XBF) {
        const float* X = (const float*)Xv;
        int row = tid >> 2, part = tid & 3;
        int gn = node0 + row;
#pragma unroll
        for (int c = 0; c < 8; ++c) {
            int k = part * 32 + c * 4;
            float4 v = (gn < n) ? *(const float4*)(X + (size_t)gn * K + k) : float4{0, 0, 0, 0};
            uint2 p = {pack2bf(v.x, v.y), pack2bf(v.z, v.w)};
            *(uint2*)(Xs + row * XS + k) = p;
        }
    } else {
        const ushort16* X = (const ushort16*)Xv;
        for (int q = tid; q < TN * K / 8; q += 256) {
            int row = q >> 4;
            int c = q & 15;
            int gn = node0 + row;
            uint4 v = (gn < n) ? ((const uint4*)(X + (size_t)gn * K))[c] : uint4{0, 0, 0, 0};
            *(uint4*)(Xs + row * XS + c * 8) = v;
        }
    }
    __syncthreads();

    constexpr int CT = M / 16;
    int w = tid >> 6;
    int lane = tid & 63;
    int l15 = lane & 15;
    int quad = lane >> 4;

    f32x4 acc[CT] = {};
    const short* xrow = Xs + (w * 16 + l15) * XS + quad * 8;
#pragma unroll
    for (int kk = 0; kk < 4; ++kk) {
        bf16x8 a = *(const bf16x8*)(xrow + kk * 32);
#pragma unroll
        for (int ct = 0; ct < CT; ++ct) {
            bf16x8 b = *(const bf16x8*)(Ws + (ct * 16 + l15) * XS + quad * 8 + kk * 32);
            acc[ct] = __builtin_amdgcn_mfma_f32_16x16x32_bf16(a, b, acc[ct], 0, 0, 0);
        }
    }

#pragma unroll
    for (int ct = 0; ct < CT; ++ct) {
#pragma unroll
        for (int r = 0; r < 4; ++r) {
            int gn = node0 + w * 16 + quad * 4 + r;
            if (gn < n) H[(size_t)gn * M + ct * 16 + l15] = f2bf(acc[ct][r]);
        }
    }
}

// ========= fused pull aggregation + self-loop + bias (+relu), bf16 H/Z =========
// FOUR nodes per wave (16 lanes each): F=128 -> 16B/lane covers the 256B row;
// F=64 -> 8B/lane covers the 128B row. 4-edge unroll -> 16 gathers in flight.
template <int F, bool RELU>
__global__ void agg_pull(const int* __restrict__ rowstart, const int2* __restrict__ adjw,
                         const float* __restrict__ dinv, const ushort16* __restrict__ H,
                         const float* __restrict__ bias, ushort16* __restrict__ Z, int n) {
    int g = threadIdx.x >> 4;  // 16-lane group
    int l = threadIdx.x & 15;
    int node = blockIdx.x * (blockDim.x >> 4) + g;
    if (node >= n) return;
    float dn = dinv[node];
    int rs = rowstart[node], re = rowstart[node + 1];
    if (F == 128) {
        // lane covers elements l*8 .. l*8+7 (16B)
        float ac[4][8] = {};
        int p = rs;
        for (; p + 4 <= re; p += 4) {
            int2 e0 = adjw[p], e1 = adjw[p + 1], e2 = adjw[p + 2], e3 = adjw[p + 3];
            uint4 h0 = *(const uint4*)(H + (size_t)e0.x * F + l * 8);
            uint4 h1 = *(const uint4*)(H + (size_t)e1.x * F + l * 8);
            uint4 h2 = *(const uint4*)(H + (size_t)e2.x * F + l * 8);
            uint4 h3 = *(const uint4*)(H + (size_t)e3.x * F + l * 8);
            float w0 = __int_as_float(e0.y), w1 = __int_as_float(e1.y);
            float w2 = __int_as_float(e2.y), w3 = __int_as_float(e3.y);
            ac[0][0] += bf_lo(h0.x) * w0; ac[0][1] += bf_hi(h0.x) * w0;
            ac[0][2] += bf_lo(h0.y) * w0; ac[0][3] += bf_hi(h0.y) * w0;
            ac[0][4] += bf_lo(h0.z) * w0; ac[0][5] += bf_hi(h0.z) * w0;
            ac[0][6] += bf_lo(h0.w) * w0; ac[0][7] += bf_hi(h0.w) * w0;
            ac[1][0] += bf_lo(h1.x) * w1; ac[1][1] += bf_hi(h1.x) * w1;
            ac[1][2] += bf_lo(h1.y) * w1; ac[1][3] += bf_hi(h1.y) * w1;
            ac[1][4] += bf_lo(h1.z) * w1; ac[1][5] += bf_hi(h1.z) * w1;
            ac[1][6] += bf_lo(h1.w) * w1; ac[1][7] += bf_hi(h1.w) * w1;
            ac[2][0] += bf_lo(h2.x) * w2; ac[2][1] += bf_hi(h2.x) * w2;
            ac[2][2] += bf_lo(h2.y) * w2; ac[2][3] += bf_hi(h2.y) * w2;
            ac[2][4] += bf_lo(h2.z) * w2; ac[2][5] += bf_hi(h2.z) * w2;
            ac[2][6] += bf_lo(h2.w) * w2; ac[2][7] += bf_hi(h2.w) * w2;
            ac[3][0] += bf_lo(h3.x) * w3; ac[3][1] += bf_hi(h3.x) * w3;
            ac[3][2] += bf_lo(h3.y) * w3; ac[3][3] += bf_hi(h3.y) * w3;
            ac[3][4] += bf_lo(h3.z) * w3; ac[3][5] += bf_hi(h3.z) * w3;
            ac[3][6] += bf_lo(h3.w) * w3; ac[3][7] += bf_hi(h3.w) * w3;
        }
        for (; p < re; ++p) {
            int2 e = adjw[p];
            float w = __int_as_float(e.y);
            uint4 h = *(const uint4*)(H + (size_t)e.x * F + l * 8);
            ac[0][0] += bf_lo(h.x) * w; ac[0][1] += bf_hi(h.x) * w;
            ac[0][2] += bf_lo(h.y) * w; ac[0][3] += bf_hi(h.y) * w;
            ac[0][4] += bf_lo(h.z) * w; ac[0][5] += bf_hi(h.z) * w;
            ac[0][6] += bf_lo(h.w) * w; ac[0][7] += bf_hi(h.w) * w;
        }
        uint4 hv = *(const uint4*)(H + (size_t)node * F + l * 8);
        float4 bv0 = *(const float4*)(bias + l * 8);
        float4 bv1 = *(const float4*)(bias + l * 8 + 4);
        float d2 = dn * dn;
        float v[8];
        float hs[8] = {bf_lo(hv.x), bf_hi(hv.x), bf_lo(hv.y), bf_hi(hv.y),
                       bf_lo(hv.z), bf_hi(hv.z), bf_lo(hv.w), bf_hi(hv.w)};
        float bb[8] = {bv0.x, bv0.y, bv0.z, bv0.w, bv1.x, bv1.y, bv1.z, bv1.w};
#pragma unroll
        for (int j = 0; j < 8; ++j) {
            v[j] = (ac[0][j] + ac[1][j]) + (ac[2][j] + ac[3][j]) + hs[j] * d2 + bb[j];
            if (RELU) v[j] = fmaxf(v[j], 0.0f);
        }
        *(uint4*)(Z + (size_t)node * F + l * 8) =
            uint4{pack2bf(v[0], v[1]), pack2bf(v[2], v[3]), pack2bf(v[4], v[5]),
                  pack2bf(v[6], v[7])};
    } else {  // F == 64: lane covers elements l*4 .. l*4+3 (8B)
        float ac[4][4] = {};
        int p = rs;
        for (; p + 4 <= re; p += 4) {
            int2 e0 = adjw[p], e1 = adjw[p + 1], e2 = adjw[p + 2], e3 = adjw[p + 3];
            uint2 h0 = *(const uint2*)(H + (size_t)e0.x * F + l * 4);
            uint2 h1 = *(const uint2*)(H + (size_t)e1.x * F + l * 4);
            uint2 h2 = *(const uint2*)(H + (size_t)e2.x * F + l * 4);
            uint2 h3 = *(const uint2*)(H + (size_t)e3.x * F + l * 4);
            float w0 = __int_as_float(e0.y), w1 = __int_as_float(e1.y);
            float w2 = __int_as_float(e2.y), w3 = __int_as_float(e3.y);
            ac[0][0] += bf_lo(h0.x) * w0; ac[0][1] += bf_hi(h0.x) * w0;
            ac[0][2] += bf_lo(h0.y) * w0; ac[0][3] += bf_hi(h0.y) * w0;
            ac[1][0] += bf_lo(h1.x) * w1; ac[1][1] += bf_hi(h1.x) * w1;
            ac[1][2] += bf_lo(h1.y) * w1; ac[1][3] += bf_hi(h1.y) * w1;
            ac[2][0] += bf_lo(h2.x) * w2; ac[2][1] += bf_hi(h2.x) * w2;
            ac[2][2] += bf_lo(h2.y) * w2; ac[2][3] += bf_hi(h2.y) * w2;
            ac[3][0] += bf_lo(h3.x) * w3; ac[3][1] += bf_hi(h3.x) * w3;
            ac[3][2] += bf_lo(h3.y) * w3; ac[3][3] += bf_hi(h3.y) * w3;
        }
        for (; p < re; ++p) {
            int2 e = adjw[p];
            float w = __int_as_float(e.y);
            uint2 h = *(const uint2*)(H + (size_t)e.x * F + l * 4);
            ac[0][0] += bf_lo(h.x) * w; ac[0][1] += bf_hi(h.x) * w;
            ac[0][2] += bf_lo(h.y) * w; ac[0][3] += bf_hi(h.y) * w;
        }
        uint2 hv = *(const uint2*)(H + (size_t)node * F + l * 4);
        float4 bv = *(const float4*)(bias + l * 4);
        float d2 = dn * dn;
        float hs[4] = {bf_lo(hv.x), bf_hi(hv.x), bf_lo(hv.y), bf_hi(hv.y)};
        float bb[4] = {bv.x, bv.y, bv.z, bv.w};
        float v[4];
#pragma unroll
        for (int j = 0; j < 4; ++j) {
            v[j] = (ac[0][j] + ac[1][j]) + (ac[2][j] + ac[3][j]) + hs[j] * d2 + bb[j];
            if (RELU) v[j] = fmaxf(v[j], 0.0f);
        }
        *(uint2*)(Z + (size_t)node * F + l * 4) = uint2{pack2bf(v[0], v[1]), pack2bf(v[2], v[3])};
    }
}

// ===== decode via MFMA: 16 edges per wave =====
__global__ void decode_mfma(const int* __restrict__ pos, const int* __restrict__ neg,
                            const short* __restrict__ Z, float* __restrict__ out) {
    int wid = threadIdx.x >> 6;
    int lane = threadIdx.x & 63;
    int l15 = lane & 15;
    int quad = lane >> 4;
    int e0 = (blockIdx.x * 4 + wid) * 16;
    if (e0 >= N_POS + N_NEG) return;
    const int* bp = (e0 < N_POS) ? pos : (neg - N_POS);
    int e = e0 + l15;
    int a = bp[e];
    int b = bp[600000 + e];  // N_POS == N_NEG == 600000

    const short* za = Z + (size_t)a * OUT_CH + quad * 8;
    const short* zb = Z + (size_t)b * OUT_CH + quad * 8;
    bf16x8 a0 = *(const bf16x8*)(za);
    bf16x8 a1 = *(const bf16x8*)(za + 32);
    bf16x8 b0 = *(const bf16x8*)(zb);
    bf16x8 b1 = *(const bf16x8*)(zb + 32);

    f32x4 acc = {};
    acc = __builtin_amdgcn_mfma_f32_16x16x32_bf16(a0, b0, acc, 0, 0, 0);
    acc = __builtin_amdgcn_mfma_f32_16x16x32_bf16(a1, b1, acc, 0, 0, 0);

    if (quad == (l15 >> 2)) out[e] = acc[l15 & 3];
}

extern "C" void kernel_launch(void* const* d_in, const int* in_sizes, int n_in,
                              void* d_out, int out_size, void* d_ws, size_t ws_size,
                              hipStream_t stream) {
    const float* x = (const float*)d_in[0];
    const int* pos = (const int*)d_in[1];  // row0 = src, row1 = dst
    const int* neg = (const int*)d_in[2];
    const float* W1 = (const float*)d_in[3];
    const float* b1 = (const float*)d_in[4];
    const float* W2 = (const float*)d_in[5];
    const float* b2 = (const float*)d_in[6];
    float* out = (float*)d_out;

    // workspace layout (bf16 intermediates)
    ushort16* A = (ushort16*)d_ws;                      // h1 [N,128]; later h2 [N,64]
    ushort16* B = A + (size_t)N_NODES * 128;            // z1 [N,128]; later z2 [N,64]
    float* dinv = (float*)(B + (size_t)N_NODES * 128);  // [N]
    int* hist = (int*)(dinv + N_NODES);                 // [N]
    int* rowstart = hist + N_NODES;                     // [N+1]
    int* cursor = rowstart + N_NODES + 1;               // [N]
    int2* adjw = (int2*)(cursor + N_NODES);             // [N_POS] (adj, wgt) pairs
    int* partials = (int*)(adjw + N_POS);               // [128]
    ushort16* W1t = (ushort16*)(partials + 128);        // [128*128]
    ushort16* W2t = W1t + 128 * 128;                    // [64*128]

    const int* pos_src = pos;
    const int* pos_dst = pos + N_POS;

    constexpr int NB_SCAN = (N_NODES + 1023) / 1024;  // 98

    // ---- CSR build + dinv + weight transpose ----
    hipMemsetAsync(hist, 0, N_NODES * sizeof(int), stream);
    hist_count<<<(N_POS + 255) / 256, 256, 0, stream>>>(pos_dst, hist, N_POS);
    scan_reduce<<<NB_SCAN, 256, 0, stream>>>(hist, partials, N_NODES);
    scan_partials<<<1, 128, 0, stream>>>(partials, NB_SCAN);
    scan_final<<<NB_SCAN, 256, 0, stream>>>(hist, partials, rowstart, cursor, dinv, N_NODES);
    csr_fill<<<(N_POS + 255) / 256, 256, 0, stream>>>(pos_src, pos_dst, dinv, cursor, adjw,
                                                      N_POS);
    wt_convert<<<(128 * 128 + 64 * 128 + 255) / 256, 256, 0, stream>>>(W1, W2, W1t, W2t);

    // ---- layer 1 ----
    gemm_mfma<HIDDEN, false><<<(N_NODES + 63) / 64, 256, 0, stream>>>(x, W1t, A, N_NODES);
    agg_pull<HIDDEN, true><<<(N_NODES + 15) / 16, 256, 0, stream>>>(rowstart, adjw, dinv, A, b1,
                                                                    B, N_NODES);

    // ---- layer 2 ----
    ushort16* h2 = A;  // [N,64]
    gemm_mfma<OUT_CH, true><<<(N_NODES + 63) / 64, 256, 0, stream>>>(B, W2t, h2, N_NODES);
    ushort16* z2 = B;  // [N,64]
    agg_pull<OUT_CH, false><<<(N_NODES + 15) / 16, 256, 0, stream>>>(rowstart, adjw, dinv, h2, b2,
                                                                     z2, N_NODES);

    // ---- decode (16 edges/wave, 64/block) ----
    decode_mfma<<<(N_POS + N_NEG) / 64, 256, 0, stream>>>(pos, neg, (const short*)z2, out);
}

// Round 9
// 284.989 us; speedup vs baseline: 2.1933x; 1.0162x over previous
//
#include <hip/hip_runtime.h>

#define N_NODES 100000
#define IN_CH 128
#define HIDDEN 128
#define OUT_CH 64
#define N_POS 600000
#define N_NEG 600000

typedef unsigned int uint32;
typedef unsigned short ushort16;
typedef __attribute__((ext_vector_type(8))) short bf16x8;
typedef __attribute__((ext_vector_type(4))) float f32x4;

// ---- bf16 helpers ----
__device__ inline float bf_lo(uint32 u) {
    union { uint32 i; float f; } v;
    v.i = u << 16;
    return v.f;
}
__device__ inline float bf_hi(uint32 u) {
    union { uint32 i; float f; } v;
    v.i = u & 0xffff0000u;
    return v.f;
}
__device__ inline ushort16 f2bf(float f) {
    union { uint32 i; float f; } v;
    v.f = f;
    uint32 r = v.i + 0x7fffu + ((v.i >> 16) & 1u);  // round-to-nearest-even
    return (ushort16)(r >> 16);
}
__device__ inline uint32 pack2bf(float a, float b) {
    return (uint32)f2bf(a) | ((uint32)f2bf(b) << 16);
}

// ================= CSR build =================
__global__ void hist_count(const int* __restrict__ dst, int* __restrict__ hist, int n_edges) {
    int i = blockIdx.x * blockDim.x + threadIdx.x;
    if (i < n_edges) atomicAdd(&hist[dst[i]], 1);
}

__global__ void scan_reduce(const int* __restrict__ hist, int* __restrict__ partials, int n) {
    __shared__ int sdata[256];
    int b = blockIdx.x, t = threadIdx.x;
    int base = b * 1024;
    int s = 0;
    for (int i = t; i < 1024; i += 256) {
        int idx = base + i;
        s += (idx < n) ? hist[idx] : 0;
    }
    sdata[t] = s;
    __syncthreads();
    for (int off = 128; off > 0; off >>= 1) {
        if (t < off) sdata[t] += sdata[t + off];
        __syncthreads();
    }
    if (t == 0) partials[b] = sdata[0];
}

// scan_final now computes its own partials-prefix (first wave) — scan_partials
// kernel eliminated. NB_SCAN = 98 <= 128.
__global__ void scan_final(const int* __restrict__ hist, const int* __restrict__ partials,
                           int* __restrict__ rowstart, int* __restrict__ cursor,
                           float* __restrict__ dinv, int n) {
    __shared__ int tsum[256];
    __shared__ int base_sh;
    int t = threadIdx.x, b = blockIdx.x;
    if (t < 64) {
        int s0 = (t < b) ? partials[t] : 0;
        int i2 = t + 64;
        int s1 = (i2 < b && i2 < 98) ? partials[i2] : 0;
        int s = s0 + s1;
#pragma unroll
        for (int off = 32; off > 0; off >>= 1) s += __shfl_down(s, off, 64);
        if (t == 0) base_sh = s;
    }
    int base = b * 1024 + t * 4;
    int v[4];
    int s = 0;
#pragma unroll
    for (int j = 0; j < 4; j++) {
        int i = base + j;
        v[j] = (i < n) ? hist[i] : 0;
        s += v[j];
    }
    tsum[t] = s;
    __syncthreads();
    for (int off = 1; off < 256; off <<= 1) {
        int a = (t >= off) ? tsum[t - off] : 0;
        __syncthreads();
        tsum[t] += a;
        __syncthreads();
    }
    int offset = base_sh + (tsum[t] - s);
#pragma unroll
    for (int j = 0; j < 4; j++) {
        int i = base + j;
        if (i < n) {
            rowstart[i] = offset;
            cursor[i] = offset;
            dinv[i] = rsqrtf((float)v[j] + 1.0f);
            offset += v[j];
        }
    }
    if (b == 0 && t == 0) rowstart[n] = N_POS;
}

// csr_fill fused with weight transpose/convert (independent work, one launch).
#define NB_FILL ((N_POS + 255) / 256)
__global__ void csr_fill_wt(const int* __restrict__ src, const int* __restrict__ dst,
                            const float* __restrict__ dinv, int* __restrict__ cursor,
                            int2* __restrict__ adjw, const float* __restrict__ W1,
                            const float* __restrict__ W2, ushort16* __restrict__ W1t,
                            ushort16* __restrict__ W2t) {
    if (blockIdx.x < NB_FILL) {
        int e = blockIdx.x * 256 + threadIdx.x;
        if (e < N_POS) {
            int s = src[e], d = dst[e];
            int p = atomicAdd(&cursor[d], 1);
            adjw[p] = int2{s, __float_as_int(dinv[s] * dinv[d])};
        }
    } else {
        int i = (blockIdx.x - NB_FILL) * 256 + threadIdx.x;
        if (i < 128 * 128) {
            int n = i >> 7, k = i & 127;
            W1t[i] = f2bf(W1[k * 128 + n]);
        } else {
            int j = i - 128 * 128;
            if (j < 64 * 128) {
                int n = j >> 7, k = j & 127;
                W2t[j] = f2bf(W2[k * 64 + n]);
            }
        }
    }
}

// ================= MFMA GEMM: H_bf16[n,M] = X[n,128] @ W[128,M] =================
template <int M, bool XBF>
__global__ __launch_bounds__(256) void gemm_mfma(const void* __restrict__ Xv,
                                                const ushort16* __restrict__ Wt,
                                                ushort16* __restrict__ H, int n) {
    constexpr int K = 128;
    constexpr int TN = 64;
    constexpr int XS = 136;  // padded LDS row stride (shorts)
    __shared__ short Xs[TN * XS];
    __shared__ short Ws[M * XS];
    int tid = threadIdx.x;
    int node0 = blockIdx.x * TN;

    for (int q = tid; q < M * K / 8; q += 256) {
        int row = q >> 4;
        int c = q & 15;
        uint4 v = ((const uint4*)Wt)[q];
        *(uint4*)(Ws + row * XS + c * 8) = v;
    }
    if (!XBF) {
        const float* X = (const float*)Xv;
        int row = tid >> 2, part = tid & 3;
        int gn = node0 + row;
#pragma unroll
        for (int c = 0; c < 8; ++c) {
            int k = part * 32 + c * 4;
            float4 v = (gn < n) ? *(const float4*)(X + (size_t)gn * K + k) : float4{0, 0, 0, 0};
            uint2 p = {pack2bf(v.x, v.y), pack2bf(v.z, v.w)};
            *(uint2*)(Xs + row * XS + k) = p;
        }
    } else {
        const ushort16* X = (const ushort16*)Xv;
        for (int q = tid; q < TN * K / 8; q += 256) {
            int row = q >> 4;
            int c = q & 15;
            int gn = node0 + row;
            uint4 v = (gn < n) ? ((const uint4*)(X + (size_t)gn * K))[c] : uint4{0, 0, 0, 0};
            *(uint4*)(Xs + row * XS + c * 8) = v;
        }
    }
    __syncthreads();

    constexpr int CT = M / 16;
    int w = tid >> 6;
    int lane = tid & 63;
    int l15 = lane & 15;
    int quad = lane >> 4;

    f32x4 acc[CT] = {};
    const short* xrow = Xs + (w * 16 + l15) * XS + quad * 8;
#pragma unroll
    for (int kk = 0; kk < 4; ++kk) {
        bf16x8 a = *(const bf16x8*)(xrow + kk * 32);
#pragma unroll
        for (int ct = 0; ct < CT; ++ct) {
            bf16x8 b = *(const bf16x8*)(Ws + (ct * 16 + l15) * XS + quad * 8 + kk * 32);
            acc[ct] = __builtin_amdgcn_mfma_f32_16x16x32_bf16(a, b, acc[ct], 0, 0, 0);
        }
    }

#pragma unroll
    for (int ct = 0; ct < CT; ++ct) {
#pragma unroll
        for (int r = 0; r < 4; ++r) {
            int gn = node0 + w * 16 + quad * 4 + r;
            if (gn < n) H[(size_t)gn * M + ct * 16 + l15] = f2bf(acc[ct][r]);
        }
    }
}

// ========= fused pull aggregation + self-loop + bias (+relu), bf16 H/Z =========
// FOUR nodes per wave (16 lanes each). Predicated straight-line 8-edge block:
// all 8 H-row gathers issue before any use (deg<=8 covers ~85% of nodes at
// mean degree 6); serial loop only for the rare tail.
template <int F, bool RELU>
__global__ void agg_pull(const int* __restrict__ rowstart, const int2* __restrict__ adjw,
                         const float* __restrict__ dinv, const ushort16* __restrict__ H,
                         const float* __restrict__ bias, ushort16* __restrict__ Z, int n) {
    int g = threadIdx.x >> 4;  // 16-lane group
    int l = threadIdx.x & 15;
    int node = blockIdx.x * (blockDim.x >> 4) + g;
    if (node >= n) return;
    float dn = dinv[node];
    int rs = rowstart[node], re = rowstart[node + 1];
    int deg = re - rs;
    int pc = (deg > 0) ? rs : (rs > 0 ? rs - 1 : 0);  // safe clamp index
    if (F == 128) {
        // lane covers elements l*8 .. l*8+7 (16B)
        uint4 h[8];
        float wv[8];
#pragma unroll
        for (int j = 0; j < 8; ++j) {
            int p = (rs + j < re) ? rs + j : pc;
            int2 e = adjw[p];
            h[j] = *(const uint4*)(H + (size_t)e.x * F + l * 8);
            wv[j] = (j < deg) ? __int_as_float(e.y) : 0.0f;
        }
        float s0[8] = {}, s1[8] = {};
#pragma unroll
        for (int j = 0; j < 8; j += 2) {
            s0[0] += bf_lo(h[j].x) * wv[j]; s0[1] += bf_hi(h[j].x) * wv[j];
            s0[2] += bf_lo(h[j].y) * wv[j]; s0[3] += bf_hi(h[j].y) * wv[j];
            s0[4] += bf_lo(h[j].z) * wv[j]; s0[5] += bf_hi(h[j].z) * wv[j];
            s0[6] += bf_lo(h[j].w) * wv[j]; s0[7] += bf_hi(h[j].w) * wv[j];
            s1[0] += bf_lo(h[j + 1].x) * wv[j + 1]; s1[1] += bf_hi(h[j + 1].x) * wv[j + 1];
            s1[2] += bf_lo(h[j + 1].y) * wv[j + 1]; s1[3] += bf_hi(h[j + 1].y) * wv[j + 1];
            s1[4] += bf_lo(h[j + 1].z) * wv[j + 1]; s1[5] += bf_hi(h[j + 1].z) * wv[j + 1];
            s1[6] += bf_lo(h[j + 1].w) * wv[j + 1]; s1[7] += bf_hi(h[j + 1].w) * wv[j + 1];
        }
        for (int p = rs + 8; p < re; ++p) {
            int2 e = adjw[p];
            float w = __int_as_float(e.y);
            uint4 hh = *(const uint4*)(H + (size_t)e.x * F + l * 8);
            s0[0] += bf_lo(hh.x) * w; s0[1] += bf_hi(hh.x) * w;
            s0[2] += bf_lo(hh.y) * w; s0[3] += bf_hi(hh.y) * w;
            s0[4] += bf_lo(hh.z) * w; s0[5] += bf_hi(hh.z) * w;
            s0[6] += bf_lo(hh.w) * w; s0[7] += bf_hi(hh.w) * w;
        }
        uint4 hv = *(const uint4*)(H + (size_t)node * F + l * 8);
        float4 bv0 = *(const float4*)(bias + l * 8);
        float4 bv1 = *(const float4*)(bias + l * 8 + 4);
        float d2 = dn * dn;
        float hs[8] = {bf_lo(hv.x), bf_hi(hv.x), bf_lo(hv.y), bf_hi(hv.y),
                       bf_lo(hv.z), bf_hi(hv.z), bf_lo(hv.w), bf_hi(hv.w)};
        float bb[8] = {bv0.x, bv0.y, bv0.z, bv0.w, bv1.x, bv1.y, bv1.z, bv1.w};
        float v[8];
#pragma unroll
        for (int j = 0; j < 8; ++j) {
            v[j] = s0[j] + s1[j] + hs[j] * d2 + bb[j];
            if (RELU) v[j] = fmaxf(v[j], 0.0f);
        }
        *(uint4*)(Z + (size_t)node * F + l * 8) =
            uint4{pack2bf(v[0], v[1]), pack2bf(v[2], v[3]), pack2bf(v[4], v[5]),
                  pack2bf(v[6], v[7])};
    } else {  // F == 64: lane covers elements l*4 .. l*4+3 (8B)
        uint2 h[8];
        float wv[8];
#pragma unroll
        for (int j = 0; j < 8; ++j) {
            int p = (rs + j < re) ? rs + j : pc;
            int2 e = adjw[p];
            h[j] = *(const uint2*)(H + (size_t)e.x * F + l * 4);
            wv[j] = (j < deg) ? __int_as_float(e.y) : 0.0f;
        }
        float s0[4] = {}, s1[4] = {};
#pragma unroll
        for (int j = 0; j < 8; j += 2) {
            s0[0] += bf_lo(h[j].x) * wv[j]; s0[1] += bf_hi(h[j].x) * wv[j];
            s0[2] += bf_lo(h[j].y) * wv[j]; s0[3] += bf_hi(h[j].y) * wv[j];
            s1[0] += bf_lo(h[j + 1].x) * wv[j + 1]; s1[1] += bf_hi(h[j + 1].x) * wv[j + 1];
            s1[2] += bf_lo(h[j + 1].y) * wv[j + 1]; s1[3] += bf_hi(h[j + 1].y) * wv[j + 1];
        }
        for (int p = rs + 8; p < re; ++p) {
            int2 e = adjw[p];
            float w = __int_as_float(e.y);
            uint2 hh = *(const uint2*)(H + (size_t)e.x * F + l * 4);
            s0[0] += bf_lo(hh.x) * w; s0[1] += bf_hi(hh.x) * w;
            s0[2] += bf_lo(hh.y) * w; s0[3] += bf_hi(hh.y) * w;
        }
        uint2 hv = *(const uint2*)(H + (size_t)node * F + l * 4);
        float4 bv = *(const float4*)(bias + l * 4);
        float d2 = dn * dn;
        float hs[4] = {bf_lo(hv.x), bf_hi(hv.x), bf_lo(hv.y), bf_hi(hv.y)};
        float bb[4] = {bv.x, bv.y, bv.z, bv.w};
        float v[4];
#pragma unroll
        for (int j = 0; j < 4; ++j) {
            v[j] = s0[j] + s1[j] + hs[j] * d2 + bb[j];
            if (RELU) v[j] = fmaxf(v[j], 0.0f);
        }
        *(uint2*)(Z + (size_t)node * F + l * 4) = uint2{pack2bf(v[0], v[1]), pack2bf(v[2], v[3])};
    }
}

// ===== decode via MFMA: 32 edges per wave (two 16-edge groups) =====
// N_POS % 32 == 0, so each wave is uniformly pos or neg.
__global__ void decode_mfma(const int* __restrict__ pos, const int* __restrict__ neg,
                            const short* __restrict__ Z, float* __restrict__ out) {
    int wid = threadIdx.x >> 6;
    int lane = threadIdx.x & 63;
    int l15 = lane & 15;
    int quad = lane >> 4;
    int e0 = (blockIdx.x * 4 + wid) * 32;
    if (e0 >= N_POS + N_NEG) return;
    const int* bp = (e0 < N_POS) ? pos : (neg - N_POS);
    int eA = e0 + l15;
    int eB = e0 + 16 + l15;
    int aA = bp[eA], bA = bp[600000 + eA];
    int aB = bp[eB], bB = bp[600000 + eB];

    const short* zaA = Z + (size_t)aA * OUT_CH + quad * 8;
    const short* zbA = Z + (size_t)bA * OUT_CH + quad * 8;
    const short* zaB = Z + (size_t)aB * OUT_CH + quad * 8;
    const short* zbB = Z + (size_t)bB * OUT_CH + quad * 8;
    bf16x8 a0A = *(const bf16x8*)(zaA);
    bf16x8 a1A = *(const bf16x8*)(zaA + 32);
    bf16x8 b0A = *(const bf16x8*)(zbA);
    bf16x8 b1A = *(const bf16x8*)(zbA + 32);
    bf16x8 a0B = *(const bf16x8*)(zaB);
    bf16x8 a1B = *(const bf16x8*)(zaB + 32);
    bf16x8 b0B = *(const bf16x8*)(zbB);
    bf16x8 b1B = *(const bf16x8*)(zbB + 32);

    f32x4 accA = {}, accB = {};
    accA = __builtin_amdgcn_mfma_f32_16x16x32_bf16(a0A, b0A, accA, 0, 0, 0);
    accB = __builtin_amdgcn_mfma_f32_16x16x32_bf16(a0B, b0B, accB, 0, 0, 0);
    accA = __builtin_amdgcn_mfma_f32_16x16x32_bf16(a1A, b1A, accA, 0, 0, 0);
    accB = __builtin_amdgcn_mfma_f32_16x16x32_bf16(a1B, b1B, accB, 0, 0, 0);

    if (quad == (l15 >> 2)) {
        out[eA] = accA[l15 & 3];
        out[eB] = accB[l15 & 3];
    }
}

extern "C" void kernel_launch(void* const* d_in, const int* in_sizes, int n_in,
                              void* d_out, int out_size, void* d_ws, size_t ws_size,
                              hipStream_t stream) {
    const float* x = (const float*)d_in[0];
    const int* pos = (const int*)d_in[1];  // row0 = src, row1 = dst
    const int* neg = (const int*)d_in[2];
    const float* W1 = (const float*)d_in[3];
    const float* b1 = (const float*)d_in[4];
    const float* W2 = (const float*)d_in[5];
    const float* b2 = (const float*)d_in[6];
    float* out = (float*)d_out;

    // workspace layout (bf16 intermediates)
    ushort16* A = (ushort16*)d_ws;                      // h1 [N,128]; later h2 [N,64]
    ushort16* B = A + (size_t)N_NODES * 128;            // z1 [N,128]; later z2 [N,64]
    float* dinv = (float*)(B + (size_t)N_NODES * 128);  // [N]
    int* hist = (int*)(dinv + N_NODES);                 // [N]
    int* rowstart = hist + N_NODES;                     // [N+1]
    int* cursor = rowstart + N_NODES + 1;               // [N]
    int2* adjw = (int2*)(cursor + N_NODES);             // [N_POS] (adj, wgt) pairs
    int* partials = (int*)(adjw + N_POS);               // [128]
    ushort16* W1t = (ushort16*)(partials + 128);        // [128*128]
    ushort16* W2t = W1t + 128 * 128;                    // [64*128]

    const int* pos_src = pos;
    const int* pos_dst = pos + N_POS;

    constexpr int NB_SCAN = (N_NODES + 1023) / 1024;  // 98

    // ---- CSR build + dinv + weight transpose ----
    hipMemsetAsync(hist, 0, N_NODES * sizeof(int), stream);
    hist_count<<<(N_POS + 255) / 256, 256, 0, stream>>>(pos_dst, hist, N_POS);
    scan_reduce<<<NB_SCAN, 256, 0, stream>>>(hist, partials, N_NODES);
    scan_final<<<NB_SCAN, 256, 0, stream>>>(hist, partials, rowstart, cursor, dinv, N_NODES);
    csr_fill_wt<<<NB_FILL + 96, 256, 0, stream>>>(pos_src, pos_dst, dinv, cursor, adjw, W1, W2,
                                                  W1t, W2t);

    // ---- layer 1 ----
    gemm_mfma<HIDDEN, false><<<(N_NODES + 63) / 64, 256, 0, stream>>>(x, W1t, A, N_NODES);
    agg_pull<HIDDEN, true><<<(N_NODES + 15) / 16, 256, 0, stream>>>(rowstart, adjw, dinv, A, b1,
                                                                    B, N_NODES);

    // ---- layer 2 ----
    ushort16* h2 = A;  // [N,64]
    gemm_mfma<OUT_CH, true><<<(N_NODES + 63) / 64, 256, 0, stream>>>(B, W2t, h2, N_NODES);
    ushort16* z2 = B;  // [N,64]
    agg_pull<OUT_CH, false><<<(N_NODES + 15) / 16, 256, 0, stream>>>(rowstart, adjw, dinv, h2, b2,
                                                                     z2, N_NODES);

    // ---- decode (32 edges/wave, 128/block) ----
    decode_mfma<<<(N_POS + N_NEG) / 128, 256, 0, stream>>>(pos, neg, (const short*)z2, out);
}

// Round 10
// 275.551 us; speedup vs baseline: 2.2684x; 1.0343x over previous
//
#include <hip/hip_runtime.h>

#define N_NODES 100000
#define IN_CH 128
#define HIDDEN 128
#define OUT_CH 64
#define N_POS 600000
#define N_NEG 600000

typedef unsigned int uint32;
typedef unsigned short ushort16;
typedef __attribute__((ext_vector_type(8))) short bf16x8;
typedef __attribute__((ext_vector_type(4))) float f32x4;

// ---- bf16 helpers ----
__device__ inline float bf_lo(uint32 u) {
    union { uint32 i; float f; } v;
    v.i = u << 16;
    return v.f;
}
__device__ inline float bf_hi(uint32 u) {
    union { uint32 i; float f; } v;
    v.i = u & 0xffff0000u;
    return v.f;
}
__device__ inline ushort16 f2bf(float f) {
    union { uint32 i; float f; } v;
    v.f = f;
    uint32 r = v.i + 0x7fffu + ((v.i >> 16) & 1u);  // round-to-nearest-even
    return (ushort16)(r >> 16);
}
__device__ inline uint32 pack2bf(float a, float b) {
    return (uint32)f2bf(a) | ((uint32)f2bf(b) << 16);
}

#define NB_HIST ((N_POS + 255) / 256)   // 2344
#define NB_FILL ((N_POS + 255) / 256)   // 2344
#define NB_GEMM1 ((N_NODES + 63) / 64)  // 1563

// ===== fused: hist_count + weight transpose/convert (independent work) =====
__global__ void hist_wt(const int* __restrict__ dst, int* __restrict__ hist,
                        const float* __restrict__ W1, const float* __restrict__ W2,
                        ushort16* __restrict__ W1t, ushort16* __restrict__ W2t) {
    if (blockIdx.x < NB_HIST) {
        int i = blockIdx.x * 256 + threadIdx.x;
        if (i < N_POS) atomicAdd(&hist[dst[i]], 1);
    } else {
        int i = (blockIdx.x - NB_HIST) * 256 + threadIdx.x;
        if (i < 128 * 128) {
            int n = i >> 7, k = i & 127;
            W1t[i] = f2bf(W1[k * 128 + n]);
        } else {
            int j = i - 128 * 128;
            if (j < 64 * 128) {
                int n = j >> 7, k = j & 127;
                W2t[j] = f2bf(W2[k * 64 + n]);
            }
        }
    }
}

__global__ void scan_reduce(const int* __restrict__ hist, int* __restrict__ partials, int n) {
    __shared__ int sdata[256];
    int b = blockIdx.x, t = threadIdx.x;
    int base = b * 1024;
    int s = 0;
    for (int i = t; i < 1024; i += 256) {
        int idx = base + i;
        s += (idx < n) ? hist[idx] : 0;
    }
    sdata[t] = s;
    __syncthreads();
    for (int off = 128; off > 0; off >>= 1) {
        if (t < off) sdata[t] += sdata[t + off];
        __syncthreads();
    }
    if (t == 0) partials[b] = sdata[0];
}

// scan_final computes its own partials-prefix (first wave). NB_SCAN = 98 <= 128.
__global__ void scan_final(const int* __restrict__ hist, const int* __restrict__ partials,
                           int* __restrict__ rowstart, int* __restrict__ cursor,
                           float* __restrict__ dinv, int n) {
    __shared__ int tsum[256];
    __shared__ int base_sh;
    int t = threadIdx.x, b = blockIdx.x;
    if (t < 64) {
        int s0 = (t < b) ? partials[t] : 0;
        int i2 = t + 64;
        int s1 = (i2 < b && i2 < 98) ? partials[i2] : 0;
        int s = s0 + s1;
#pragma unroll
        for (int off = 32; off > 0; off >>= 1) s += __shfl_down(s, off, 64);
        if (t == 0) base_sh = s;
    }
    int base = b * 1024 + t * 4;
    int v[4];
    int s = 0;
#pragma unroll
    for (int j = 0; j < 4; j++) {
        int i = base + j;
        v[j] = (i < n) ? hist[i] : 0;
        s += v[j];
    }
    tsum[t] = s;
    __syncthreads();
    for (int off = 1; off < 256; off <<= 1) {
        int a = (t >= off) ? tsum[t - off] : 0;
        __syncthreads();
        tsum[t] += a;
        __syncthreads();
    }
    int offset = base_sh + (tsum[t] - s);
#pragma unroll
    for (int j = 0; j < 4; j++) {
        int i = base + j;
        if (i < n) {
            rowstart[i] = offset;
            cursor[i] = offset;
            dinv[i] = rsqrtf((float)v[j] + 1.0f);
            offset += v[j];
        }
    }
    if (b == 0 && t == 0) rowstart[n] = N_POS;
}

// ===== shared GEMM tile body: H_bf16[node0..node0+64, M] = X @ W =====
template <int M, bool XBF>
__device__ __forceinline__ void gemm_tile(const void* __restrict__ Xv,
                                          const ushort16* __restrict__ Wt,
                                          ushort16* __restrict__ H, int n, int tileIdx) {
    constexpr int K = 128;
    constexpr int TN = 64;
    constexpr int XS = 136;  // padded LDS row stride (shorts)
    __shared__ short Xs[TN * XS];
    __shared__ short Ws[M * XS];
    int tid = threadIdx.x;
    int node0 = tileIdx * TN;

    for (int q = tid; q < M * K / 8; q += 256) {
        int row = q >> 4;
        int c = q & 15;
        uint4 v = ((const uint4*)Wt)[q];
        *(uint4*)(Ws + row * XS + c * 8) = v;
    }
    if (!XBF) {
        const float* X = (const float*)Xv;
        int row = tid >> 2, part = tid & 3;
        int gn = node0 + row;
#pragma unroll
        for (int c = 0; c < 8; ++c) {
            int k = part * 32 + c * 4;
            float4 v = (gn < n) ? *(const float4*)(X + (size_t)gn * K + k) : float4{0, 0, 0, 0};
            uint2 p = {pack2bf(v.x, v.y), pack2bf(v.z, v.w)};
            *(uint2*)(Xs + row * XS + k) = p;
        }
    } else {
        const ushort16* X = (const ushort16*)Xv;
        for (int q = tid; q < TN * K / 8; q += 256) {
            int row = q >> 4;
            int c = q & 15;
            int gn = node0 + row;
            uint4 v = (gn < n) ? ((const uint4*)(X + (size_t)gn * K))[c] : uint4{0, 0, 0, 0};
            *(uint4*)(Xs + row * XS + c * 8) = v;
        }
    }
    __syncthreads();

    constexpr int CT = M / 16;
    int w = tid >> 6;
    int lane = tid & 63;
    int l15 = lane & 15;
    int quad = lane >> 4;

    f32x4 acc[CT] = {};
    const short* xrow = Xs + (w * 16 + l15) * XS + quad * 8;
#pragma unroll
    for (int kk = 0; kk < 4; ++kk) {
        bf16x8 a = *(const bf16x8*)(xrow + kk * 32);
#pragma unroll
        for (int ct = 0; ct < CT; ++ct) {
            bf16x8 b = *(const bf16x8*)(Ws + (ct * 16 + l15) * XS + quad * 8 + kk * 32);
            acc[ct] = __builtin_amdgcn_mfma_f32_16x16x32_bf16(a, b, acc[ct], 0, 0, 0);
        }
    }

#pragma unroll
    for (int ct = 0; ct < CT; ++ct) {
#pragma unroll
        for (int r = 0; r < 4; ++r) {
            int gn = node0 + w * 16 + quad * 4 + r;
            if (gn < n) H[(size_t)gn * M + ct * 16 + l15] = f2bf(acc[ct][r]);
        }
    }
}

// ===== fused: csr_fill (scattered, latency-bound) + layer-1 GEMM (MFMA-bound) =====
// Independent work co-scheduled in one launch so the scatter's dead cycles are
// filled by GEMM waves (m114: MFMA wave + other-pipe wave overlap ≈ max not sum).
__global__ __launch_bounds__(256) void csr_gemm1(
    const int* __restrict__ src, const int* __restrict__ dst, const float* __restrict__ dinv,
    int* __restrict__ cursor, int2* __restrict__ adjw, const float* __restrict__ x,
    const ushort16* __restrict__ W1t, ushort16* __restrict__ H, int n) {
    if (blockIdx.x < NB_FILL) {
        int e = blockIdx.x * 256 + threadIdx.x;
        if (e < N_POS) {
            int s = src[e], d = dst[e];
            int p = atomicAdd(&cursor[d], 1);
            adjw[p] = int2{s, __float_as_int(dinv[s] * dinv[d])};
        }
    } else {
        gemm_tile<HIDDEN, false>(x, W1t, H, n, blockIdx.x - NB_FILL);
    }
}

// standalone layer-2 GEMM
template <int M, bool XBF>
__global__ __launch_bounds__(256) void gemm_mfma(const void* __restrict__ Xv,
                                                 const ushort16* __restrict__ Wt,
                                                 ushort16* __restrict__ H, int n) {
    gemm_tile<M, XBF>(Xv, Wt, H, n, blockIdx.x);
}

// ========= fused pull aggregation + self-loop + bias (+relu), bf16 H/Z =========
// FOUR nodes per wave (16 lanes each). Predicated straight-line 8-edge block.
template <int F, bool RELU>
__global__ void agg_pull(const int* __restrict__ rowstart, const int2* __restrict__ adjw,
                         const float* __restrict__ dinv, const ushort16* __restrict__ H,
                         const float* __restrict__ bias, ushort16* __restrict__ Z, int n) {
    int g = threadIdx.x >> 4;  // 16-lane group
    int l = threadIdx.x & 15;
    int node = blockIdx.x * (blockDim.x >> 4) + g;
    if (node >= n) return;
    float dn = dinv[node];
    int rs = rowstart[node], re = rowstart[node + 1];
    int deg = re - rs;
    int pc = (deg > 0) ? rs : (rs > 0 ? rs - 1 : 0);  // safe clamp index
    if (F == 128) {
        uint4 h[8];
        float wv[8];
#pragma unroll
        for (int j = 0; j < 8; ++j) {
            int p = (rs + j < re) ? rs + j : pc;
            int2 e = adjw[p];
            h[j] = *(const uint4*)(H + (size_t)e.x * F + l * 8);
            wv[j] = (j < deg) ? __int_as_float(e.y) : 0.0f;
        }
        float s0[8] = {}, s1[8] = {};
#pragma unroll
        for (int j = 0; j < 8; j += 2) {
            s0[0] += bf_lo(h[j].x) * wv[j]; s0[1] += bf_hi(h[j].x) * wv[j];
            s0[2] += bf_lo(h[j].y) * wv[j]; s0[3] += bf_hi(h[j].y) * wv[j];
            s0[4] += bf_lo(h[j].z) * wv[j]; s0[5] += bf_hi(h[j].z) * wv[j];
            s0[6] += bf_lo(h[j].w) * wv[j]; s0[7] += bf_hi(h[j].w) * wv[j];
            s1[0] += bf_lo(h[j + 1].x) * wv[j + 1]; s1[1] += bf_hi(h[j + 1].x) * wv[j + 1];
            s1[2] += bf_lo(h[j + 1].y) * wv[j + 1]; s1[3] += bf_hi(h[j + 1].y) * wv[j + 1];
            s1[4] += bf_lo(h[j + 1].z) * wv[j + 1]; s1[5] += bf_hi(h[j + 1].z) * wv[j + 1];
            s1[6] += bf_lo(h[j + 1].w) * wv[j + 1]; s1[7] += bf_hi(h[j + 1].w) * wv[j + 1];
        }
        for (int p = rs + 8; p < re; ++p) {
            int2 e = adjw[p];
            float w = __int_as_float(e.y);
            uint4 hh = *(const uint4*)(H + (size_t)e.x * F + l * 8);
            s0[0] += bf_lo(hh.x) * w; s0[1] += bf_hi(hh.x) * w;
            s0[2] += bf_lo(hh.y) * w; s0[3] += bf_hi(hh.y) * w;
            s0[4] += bf_lo(hh.z) * w; s0[5] += bf_hi(hh.z) * w;
            s0[6] += bf_lo(hh.w) * w; s0[7] += bf_hi(hh.w) * w;
        }
        uint4 hv = *(const uint4*)(H + (size_t)node * F + l * 8);
        float4 bv0 = *(const float4*)(bias + l * 8);
        float4 bv1 = *(const float4*)(bias + l * 8 + 4);
        float d2 = dn * dn;
        float hs[8] = {bf_lo(hv.x), bf_hi(hv.x), bf_lo(hv.y), bf_hi(hv.y),
                       bf_lo(hv.z), bf_hi(hv.z), bf_lo(hv.w), bf_hi(hv.w)};
        float bb[8] = {bv0.x, bv0.y, bv0.z, bv0.w, bv1.x, bv1.y, bv1.z, bv1.w};
        float v[8];
#pragma unroll
        for (int j = 0; j < 8; ++j) {
            v[j] = s0[j] + s1[j] + hs[j] * d2 + bb[j];
            if (RELU) v[j] = fmaxf(v[j], 0.0f);
        }
        *(uint4*)(Z + (size_t)node * F + l * 8) =
            uint4{pack2bf(v[0], v[1]), pack2bf(v[2], v[3]), pack2bf(v[4], v[5]),
                  pack2bf(v[6], v[7])};
    } else {  // F == 64
        uint2 h[8];
        float wv[8];
#pragma unroll
        for (int j = 0; j < 8; ++j) {
            int p = (rs + j < re) ? rs + j : pc;
            int2 e = adjw[p];
            h[j] = *(const uint2*)(H + (size_t)e.x * F + l * 4);
            wv[j] = (j < deg) ? __int_as_float(e.y) : 0.0f;
        }
        float s0[4] = {}, s1[4] = {};
#pragma unroll
        for (int j = 0; j < 8; j += 2) {
            s0[0] += bf_lo(h[j].x) * wv[j]; s0[1] += bf_hi(h[j].x) * wv[j];
            s0[2] += bf_lo(h[j].y) * wv[j]; s0[3] += bf_hi(h[j].y) * wv[j];
            s1[0] += bf_lo(h[j + 1].x) * wv[j + 1]; s1[1] += bf_hi(h[j + 1].x) * wv[j + 1];
            s1[2] += bf_lo(h[j + 1].y) * wv[j + 1]; s1[3] += bf_hi(h[j + 1].y) * wv[j + 1];
        }
        for (int p = rs + 8; p < re; ++p) {
            int2 e = adjw[p];
            float w = __int_as_float(e.y);
            uint2 hh = *(const uint2*)(H + (size_t)e.x * F + l * 4);
            s0[0] += bf_lo(hh.x) * w; s0[1] += bf_hi(hh.x) * w;
            s0[2] += bf_lo(hh.y) * w; s0[3] += bf_hi(hh.y) * w;
        }
        uint2 hv = *(const uint2*)(H + (size_t)node * F + l * 4);
        float4 bv = *(const float4*)(bias + l * 4);
        float d2 = dn * dn;
        float hs[4] = {bf_lo(hv.x), bf_hi(hv.x), bf_lo(hv.y), bf_hi(hv.y)};
        float bb[4] = {bv.x, bv.y, bv.z, bv.w};
        float v[4];
#pragma unroll
        for (int j = 0; j < 4; ++j) {
            v[j] = s0[j] + s1[j] + hs[j] * d2 + bb[j];
            if (RELU) v[j] = fmaxf(v[j], 0.0f);
        }
        *(uint2*)(Z + (size_t)node * F + l * 4) = uint2{pack2bf(v[0], v[1]), pack2bf(v[2], v[3])};
    }
}

// ===== decode via MFMA: 32 edges per wave (two 16-edge groups) =====
__global__ void decode_mfma(const int* __restrict__ pos, const int* __restrict__ neg,
                            const short* __restrict__ Z, float* __restrict__ out) {
    int wid = threadIdx.x >> 6;
    int lane = threadIdx.x & 63;
    int l15 = lane & 15;
    int quad = lane >> 4;
    int e0 = (blockIdx.x * 4 + wid) * 32;
    if (e0 >= N_POS + N_NEG) return;
    const int* bp = (e0 < N_POS) ? pos : (neg - N_POS);
    int eA = e0 + l15;
    int eB = e0 + 16 + l15;
    int aA = bp[eA], bA = bp[600000 + eA];
    int aB = bp[eB], bB = bp[600000 + eB];

    const short* zaA = Z + (size_t)aA * OUT_CH + quad * 8;
    const short* zbA = Z + (size_t)bA * OUT_CH + quad * 8;
    const short* zaB = Z + (size_t)aB * OUT_CH + quad * 8;
    const short* zbB = Z + (size_t)bB * OUT_CH + quad * 8;
    bf16x8 a0A = *(const bf16x8*)(zaA);
    bf16x8 a1A = *(const bf16x8*)(zaA + 32);
    bf16x8 b0A = *(const bf16x8*)(zbA);
    bf16x8 b1A = *(const bf16x8*)(zbA + 32);
    bf16x8 a0B = *(const bf16x8*)(zaB);
    bf16x8 a1B = *(const bf16x8*)(zaB + 32);
    bf16x8 b0B = *(const bf16x8*)(zbB);
    bf16x8 b1B = *(const bf16x8*)(zbB + 32);

    f32x4 accA = {}, accB = {};
    accA = __builtin_amdgcn_mfma_f32_16x16x32_bf16(a0A, b0A, accA, 0, 0, 0);
    accB = __builtin_amdgcn_mfma_f32_16x16x32_bf16(a0B, b0B, accB, 0, 0, 0);
    accA = __builtin_amdgcn_mfma_f32_16x16x32_bf16(a1A, b1A, accA, 0, 0, 0);
    accB = __builtin_amdgcn_mfma_f32_16x16x32_bf16(a1B, b1B, accB, 0, 0, 0);

    if (quad == (l15 >> 2)) {
        out[eA] = accA[l15 & 3];
        out[eB] = accB[l15 & 3];
    }
}

extern "C" void kernel_launch(void* const* d_in, const int* in_sizes, int n_in,
                              void* d_out, int out_size, void* d_ws, size_t ws_size,
                              hipStream_t stream) {
    const float* x = (const float*)d_in[0];
    const int* pos = (const int*)d_in[1];  // row0 = src, row1 = dst
    const int* neg = (const int*)d_in[2];
    const float* W1 = (const float*)d_in[3];
    const float* b1 = (const float*)d_in[4];
    const float* W2 = (const float*)d_in[5];
    const float* b2 = (const float*)d_in[6];
    float* out = (float*)d_out;

    // workspace layout (bf16 intermediates)
    ushort16* A = (ushort16*)d_ws;                      // h1 [N,128]; later h2 [N,64]
    ushort16* B = A + (size_t)N_NODES * 128;            // z1 [N,128]; later z2 [N,64]
    float* dinv = (float*)(B + (size_t)N_NODES * 128);  // [N]
    int* hist = (int*)(dinv + N_NODES);                 // [N]
    int* rowstart = hist + N_NODES;                     // [N+1]
    int* cursor = rowstart + N_NODES + 1;               // [N]
    int2* adjw = (int2*)(cursor + N_NODES);             // [N_POS] (adj, wgt) pairs
    int* partials = (int*)(adjw + N_POS);               // [128]
    ushort16* W1t = (ushort16*)(partials + 128);        // [128*128]
    ushort16* W2t = W1t + 128 * 128;                    // [64*128]

    const int* pos_src = pos;
    const int* pos_dst = pos + N_POS;

    constexpr int NB_SCAN = (N_NODES + 1023) / 1024;  // 98

    // ---- CSR build + dinv + weight convert ----
    hipMemsetAsync(hist, 0, N_NODES * sizeof(int), stream);
    hist_wt<<<NB_HIST + 96, 256, 0, stream>>>(pos_dst, hist, W1, W2, W1t, W2t);
    scan_reduce<<<NB_SCAN, 256, 0, stream>>>(hist, partials, N_NODES);
    scan_final<<<NB_SCAN, 256, 0, stream>>>(hist, partials, rowstart, cursor, dinv, N_NODES);

    // ---- csr_fill + layer-1 GEMM fused (independent; overlap scatter latency with MFMA) ----
    csr_gemm1<<<NB_FILL + NB_GEMM1, 256, 0, stream>>>(pos_src, pos_dst, dinv, cursor, adjw, x,
                                                      W1t, A, N_NODES);

    // ---- layer 1 aggregation ----
    agg_pull<HIDDEN, true><<<(N_NODES + 15) / 16, 256, 0, stream>>>(rowstart, adjw, dinv, A, b1,
                                                                    B, N_NODES);

    // ---- layer 2 ----
    ushort16* h2 = A;  // [N,64]
    gemm_mfma<OUT_CH, true><<<(N_NODES + 63) / 64, 256, 0, stream>>>(B, W2t, h2, N_NODES);
    ushort16* z2 = B;  // [N,64]
    agg_pull<OUT_CH, false><<<(N_NODES + 15) / 16, 256, 0, stream>>>(rowstart, adjw, dinv, h2, b2,
                                                                     z2, N_NODES);

    // ---- decode (32 edges/wave, 128/block) ----
    decode_mfma<<<(N_POS + N_NEG) / 128, 256, 0, stream>>>(pos, neg, (const short*)z2, out);
}